// Round 1
// baseline (1811.036 us; speedup 1.0000x reference)
//
#include <hip/hip_runtime.h>

// ---------------------------------------------------------------------------
// CustomGCN: 2 dense layers + 3 GCNConv layers + per-layer (max||mean) pool.
// f32 baseline. CSC built on-device each call (deterministic up to f32
// reassociation from atomic slot allocation, far below the 2% threshold).
// ---------------------------------------------------------------------------

__global__ __launch_bounds__(256) void k_init(float* __restrict__ deg, int* __restrict__ cntN,
                                              float* __restrict__ gmax, float* __restrict__ gsum,
                                              float* __restrict__ cntG, int n, int npool, int g)
{
    int i = blockIdx.x * 256 + threadIdx.x;
    if (i < n) { deg[i] = 1.0f; cntN[i] = 0; }          // deg starts at 1 (self-loop)
    if (i < npool) { gmax[i] = 0.0f; gsum[i] = 0.0f; }  // relu => max identity 0 is safe
    if (i < g) cntG[i] = 0.0f;
}

__global__ __launch_bounds__(256) void k_edge_scatter(const int* __restrict__ ei,
                                                      const float* __restrict__ ew,
                                                      float* deg, int* cntN, int e)
{
    int i = blockIdx.x * 256 + threadIdx.x;
    if (i >= e) return;
    int c = ei[e + i];          // col
    atomicAdd(&deg[c], ew[i]);
    atomicAdd(&cntN[c], 1);
}

__global__ __launch_bounds__(256) void k_dinv_cnt(float* deg, const int* __restrict__ batch,
                                                  float* cntG, int n)
{
    int i = blockIdx.x * 256 + threadIdx.x;
    if (i >= n) return;
    deg[i] = 1.0f / sqrtf(deg[i]);   // deg >= 1 always
    atomicAdd(&cntG[batch[i]], 1.0f);
}

// ---- exclusive scan of cntN[0..n) into start[0..n), 1024 elems/block -------
__global__ __launch_bounds__(256) void k_scan1(const int* __restrict__ cnt, int* __restrict__ start,
                                               int* __restrict__ partials, int n)
{
    __shared__ int s[256];
    int t = threadIdx.x;
    int base = blockIdx.x * 1024 + t * 4;
    int v[4];
#pragma unroll
    for (int j = 0; j < 4; ++j) { int idx = base + j; v[j] = (idx < n) ? cnt[idx] : 0; }
    int tsum = v[0] + v[1] + v[2] + v[3];
    s[t] = tsum; __syncthreads();
    for (int off = 1; off < 256; off <<= 1) {
        int xv = (t >= off) ? s[t - off] : 0;
        __syncthreads();
        s[t] += xv;
        __syncthreads();
    }
    if (t == 255) partials[blockIdx.x] = s[255];
    int run = s[t] - tsum;  // exclusive prefix of this thread
#pragma unroll
    for (int j = 0; j < 4; ++j) { int idx = base + j; if (idx < n) start[idx] = run; run += v[j]; }
}

__global__ __launch_bounds__(256) void k_scan2(int* partials, int nb)
{
    __shared__ int s[256];
    int t = threadIdx.x;
    int offset = 0;
    for (int b0 = 0; b0 < nb; b0 += 256) {
        int v = (b0 + t < nb) ? partials[b0 + t] : 0;
        s[t] = v; __syncthreads();
        for (int off = 1; off < 256; off <<= 1) {
            int xv = (t >= off) ? s[t - off] : 0;
            __syncthreads();
            s[t] += xv;
            __syncthreads();
        }
        int excl = s[t] - v;
        int tot = s[255];
        if (b0 + t < nb) partials[b0 + t] = offset + excl;
        offset += tot;
        __syncthreads();
    }
}

__global__ __launch_bounds__(256) void k_scan3(int* __restrict__ start, int* __restrict__ pos,
                                               const int* __restrict__ partials, int n, int total)
{
    int i = blockIdx.x * 256 + threadIdx.x;
    if (i < n) {
        int v = start[i] + partials[i >> 10];
        start[i] = v;
        pos[i] = v;
    }
    if (i == 0) start[n] = total;
}

__global__ __launch_bounds__(256) void k_fill(const int* __restrict__ ei, const float* __restrict__ ew,
                                              const float* __restrict__ dinv, int* pos,
                                              int* __restrict__ csrc, float* __restrict__ cw, int e)
{
    int i = blockIdx.x * 256 + threadIdx.x;
    if (i >= e) return;
    int r = ei[i], c = ei[e + i];
    int idx = atomicAdd(&pos[c], 1);
    csrc[idx] = r;
    cw[idx]   = dinv[r] * ew[i] * dinv[c];
}

// ---- C[M,128] = A[M,128] @ W[128,128] (+bias)(+relu) -----------------------
// Block: 256 threads, 32 rows. W + x-tile staged in LDS (80 KiB -> 2 blk/CU).
// Thread micro-tile: 4 rows x 4 cols, cols strided by 32 (conflict-free b32).
__global__ __launch_bounds__(256, 2) void k_gemm(const float* __restrict__ A, const float* __restrict__ W,
                                                 const float* __restrict__ bias, float* __restrict__ C,
                                                 int relu, int M)
{
    __shared__ float sW[16384];
    __shared__ float sX[4096];
    int t = threadIdx.x;
    {
        const float4* W4 = (const float4*)W;
        float4* sW4 = (float4*)sW;
#pragma unroll
        for (int i = 0; i < 16; ++i) sW4[t + i * 256] = W4[t + i * 256];
    }
    int r0 = blockIdx.x * 32;
    {
        const float4* A4 = (const float4*)A;
        float4* sX4 = (float4*)sX;
#pragma unroll
        for (int i = 0; i < 4; ++i) {
            int idx = t + i * 256;       // float4 index in tile [0,1024)
            int rl = idx >> 5;           // local row (32 float4 per row)
            float4 v = make_float4(0.f, 0.f, 0.f, 0.f);
            if (r0 + rl < M) v = A4[(size_t)r0 * 32 + idx];
            sX4[idx] = v;
        }
    }
    __syncthreads();

    int tc = t & 31;   // column lane: cols {tc, tc+32, tc+64, tc+96}
    int tr = t >> 5;   // row group:   rows {tr*4 .. tr*4+3}
    float acc[4][4];
#pragma unroll
    for (int m = 0; m < 4; ++m)
#pragma unroll
        for (int nn = 0; nn < 4; ++nn) acc[m][nn] = 0.f;

#pragma unroll 4
    for (int k = 0; k < 128; ++k) {
        float b0 = sW[k * 128 + tc];
        float b1 = sW[k * 128 + tc + 32];
        float b2 = sW[k * 128 + tc + 64];
        float b3 = sW[k * 128 + tc + 96];
        float a0 = sX[(tr * 4 + 0) * 128 + k];
        float a1 = sX[(tr * 4 + 1) * 128 + k];
        float a2 = sX[(tr * 4 + 2) * 128 + k];
        float a3 = sX[(tr * 4 + 3) * 128 + k];
        acc[0][0] = fmaf(a0, b0, acc[0][0]); acc[0][1] = fmaf(a0, b1, acc[0][1]);
        acc[0][2] = fmaf(a0, b2, acc[0][2]); acc[0][3] = fmaf(a0, b3, acc[0][3]);
        acc[1][0] = fmaf(a1, b0, acc[1][0]); acc[1][1] = fmaf(a1, b1, acc[1][1]);
        acc[1][2] = fmaf(a1, b2, acc[1][2]); acc[1][3] = fmaf(a1, b3, acc[1][3]);
        acc[2][0] = fmaf(a2, b0, acc[2][0]); acc[2][1] = fmaf(a2, b1, acc[2][1]);
        acc[2][2] = fmaf(a2, b2, acc[2][2]); acc[2][3] = fmaf(a2, b3, acc[2][3]);
        acc[3][0] = fmaf(a3, b0, acc[3][0]); acc[3][1] = fmaf(a3, b1, acc[3][1]);
        acc[3][2] = fmaf(a3, b2, acc[3][2]); acc[3][3] = fmaf(a3, b3, acc[3][3]);
    }

#pragma unroll
    for (int m = 0; m < 4; ++m) {
        int row = r0 + tr * 4 + m;
        if (row >= M) continue;
#pragma unroll
        for (int nn = 0; nn < 4; ++nn) {
            int col = tc + nn * 32;
            float v = acc[m][nn];
            if (bias) v += bias[col];
            if (relu) v = fmaxf(v, 0.f);
            C[(size_t)row * 128 + col] = v;
        }
    }
}

// ---- pull aggregation: one wave per dst node, float2 per lane --------------
__global__ __launch_bounds__(256) void k_agg(const float* __restrict__ xw, const int* __restrict__ start,
                                             const int* __restrict__ csrc, const float* __restrict__ cw,
                                             const float* __restrict__ dinv, const float* __restrict__ bias,
                                             float* __restrict__ hout, int n)
{
    int wid  = (blockIdx.x * 256 + threadIdx.x) >> 6;
    int lane = threadIdx.x & 63;
    if (wid >= n) return;
    const float2* xw2 = (const float2*)xw;
    float di = dinv[wid];
    float sn = di * di;                       // self-loop norm
    float2 v = xw2[(size_t)wid * 64 + lane];
    float ax = v.x * sn, ay = v.y * sn;
    int s0 = start[wid], s1 = start[wid + 1];
    for (int j = s0; j < s1; ++j) {
        int s = csrc[j];
        float w = cw[j];
        float2 u = xw2[(size_t)s * 64 + lane];
        ax = fmaf(w, u.x, ax);
        ay = fmaf(w, u.y, ay);
    }
    ax = fmaxf(ax + bias[lane * 2], 0.f);
    ay = fmaxf(ay + bias[lane * 2 + 1], 0.f);
    float2 r; r.x = ax; r.y = ay;
    ((float2*)hout)[(size_t)wid * 64 + lane] = r;
}

// ---- pooling: run-based pre-reduction over sorted batch, atomic flush ------
// h >= 0 (post-relu) => float atomicMax via uint punning is order-correct.
__global__ __launch_bounds__(256) void k_pool(const float* __restrict__ h, const int* __restrict__ batch,
                                              float* gmax, float* gsum, int n)
{
    int c = threadIdx.x & 127, sub = threadIdx.x >> 7;
    int r0 = blockIdx.x * 128;
    int rend = min(r0 + 128, n);
    float mx = 0.f, sm = 0.f;
    int cur = -1;
    for (int r = r0 + sub; r < rend; r += 2) {
        int b = batch[r];
        if (b != cur) {
            if (cur >= 0) {
                atomicMax((unsigned int*)&gmax[cur * 128 + c], __float_as_uint(mx));
                atomicAdd(&gsum[cur * 128 + c], sm);
            }
            cur = b; mx = 0.f; sm = 0.f;
        }
        float v = h[(size_t)r * 128 + c];
        mx = fmaxf(mx, v);
        sm += v;
    }
    if (cur >= 0) {
        atomicMax((unsigned int*)&gmax[cur * 128 + c], __float_as_uint(mx));
        atomicAdd(&gsum[cur * 128 + c], sm);
    }
}

__global__ __launch_bounds__(256) void k_final(const float* __restrict__ gmax, const float* __restrict__ gsum,
                                               const float* __restrict__ cntG, float* __restrict__ out,
                                               int G, int L)
{
    int i = blockIdx.x * 256 + threadIdx.x;
    int tot = L * G * 128;
    if (i >= tot) return;
    int c = i & 127;
    int g = (i >> 7) % G;
    int l = i / (G * 128);
    float ct = fmaxf(cntG[g], 1.0f);
    out[(size_t)g * (L * 256) + l * 256 + c]       = gmax[i];
    out[(size_t)g * (L * 256) + l * 256 + 128 + c] = gsum[i] / ct;
}

static inline int divup(int a, int b) { return (a + b - 1) / b; }

extern "C" void kernel_launch(void* const* d_in, const int* in_sizes, int n_in,
                              void* d_out, int out_size, void* d_ws, size_t ws_size,
                              hipStream_t stream)
{
    const float* x     = (const float*)d_in[0];
    const float* ew    = (const float*)d_in[1];
    const float* W1    = (const float*)d_in[2];
    const float* b1    = (const float*)d_in[3];
    const float* W2    = (const float*)d_in[4];
    const float* b2    = (const float*)d_in[5];
    const float* cW    = (const float*)d_in[6];
    const float* cB    = (const float*)d_in[7];
    const int*   ei    = (const int*)d_in[8];
    const int*   batch = (const int*)d_in[9];
    float* out = (float*)d_out;

    const int E = in_sizes[1];
    const int N = in_sizes[9];
    const int L = in_sizes[7] / 128;
    const int G = out_size / (L * 256);

    char* p = (char*)d_ws;
    auto carve = [&](size_t bytes) -> void* {
        void* q = (void*)p;
        p += (bytes + 255) & ~(size_t)255;
        return q;
    };
    float* dinv     = (float*)carve((size_t)N * 4);        // deg, then 1/sqrt in place
    int*   cntN     = (int*)  carve((size_t)N * 4);
    int*   start    = (int*)  carve((size_t)(N + 1) * 4);
    int*   pos      = (int*)  carve((size_t)N * 4);
    int*   partials = (int*)  carve(4096);
    int*   csrc     = (int*)  carve((size_t)E * 4);
    float* cw       = (float*)carve((size_t)E * 4);
    float* gmax     = (float*)carve((size_t)L * G * 128 * 4);
    float* gsum     = (float*)carve((size_t)L * G * 128 * 4);
    float* cntG     = (float*)carve((size_t)G * 4);
    float* bufA     = (float*)carve((size_t)N * 128 * 4);
    float* bufB     = (float*)carve((size_t)N * 128 * 4);

    const int npool = L * G * 128;

    // --- preprocessing -----------------------------------------------------
    {
        int mx = N > npool ? N : npool;
        k_init<<<divup(mx, 256), 256, 0, stream>>>(dinv, cntN, gmax, gsum, cntG, N, npool, G);
    }
    k_edge_scatter<<<divup(E, 256), 256, 0, stream>>>(ei, ew, dinv, cntN, E);
    k_dinv_cnt<<<divup(N, 256), 256, 0, stream>>>(dinv, batch, cntG, N);

    int nb1 = divup(N, 1024);
    k_scan1<<<nb1, 256, 0, stream>>>(cntN, start, partials, N);
    k_scan2<<<1, 256, 0, stream>>>(partials, nb1);
    k_scan3<<<divup(N, 256), 256, 0, stream>>>(start, pos, partials, N, E);
    k_fill<<<divup(E, 256), 256, 0, stream>>>(ei, ew, dinv, pos, csrc, cw, E);

    // --- dense encoder -----------------------------------------------------
    int gblocks = divup(N, 32);
    k_gemm<<<gblocks, 256, 0, stream>>>(x,    W1, b1, bufA, 1, N);
    k_gemm<<<gblocks, 256, 0, stream>>>(bufA, W2, b2, bufB, 1, N);

    // --- conv layers + pooling --------------------------------------------
    int ablocks = divup(N, 4);
    int pblocks = divup(N, 128);
    for (int l = 0; l < L; ++l) {
        k_gemm<<<gblocks, 256, 0, stream>>>(bufB, cW + (size_t)l * 128 * 128, nullptr, bufA, 0, N);
        k_agg<<<ablocks, 256, 0, stream>>>(bufA, start, csrc, cw, dinv, cB + (size_t)l * 128, bufB, N);
        k_pool<<<pblocks, 256, 0, stream>>>(bufB, batch, gmax + (size_t)l * G * 128, gsum + (size_t)l * G * 128, N);
    }

    k_final<<<divup(L * G * 128, 256), 256, 0, stream>>>(gmax, gsum, cntG, out, G, L);
}

// Round 2
// 1176.994 us; speedup vs baseline: 1.5387x; 1.5387x over previous
//
#include <hip/hip_runtime.h>

// ---------------------------------------------------------------------------
// CustomGCN: 2 dense layers + 3 GCNConv layers + per-layer (max||mean) pool.
// f32 baseline. CSC built on-device each call (deterministic up to f32
// reassociation from atomic slot allocation, far below the 2% threshold).
// R1: removed 100k-atomics-onto-64-addresses cntG wall (634us) -> binary
//     search on sorted batch.
// ---------------------------------------------------------------------------

__global__ __launch_bounds__(256) void k_init(float* __restrict__ deg, int* __restrict__ cntN,
                                              float* __restrict__ gmax, float* __restrict__ gsum,
                                              int n, int npool)
{
    int i = blockIdx.x * 256 + threadIdx.x;
    if (i < n) { deg[i] = 1.0f; cntN[i] = 0; }          // deg starts at 1 (self-loop)
    if (i < npool) { gmax[i] = 0.0f; gsum[i] = 0.0f; }  // relu => max identity 0 is safe
}

__global__ __launch_bounds__(256) void k_edge_scatter(const int* __restrict__ ei,
                                                      const float* __restrict__ ew,
                                                      float* deg, int* cntN, int e)
{
    int i = blockIdx.x * 256 + threadIdx.x;
    if (i >= e) return;
    int c = ei[e + i];          // col
    atomicAdd(&deg[c], ew[i]);
    atomicAdd(&cntN[c], 1);
}

__global__ __launch_bounds__(256) void k_dinv(float* deg, int n)
{
    int i = blockIdx.x * 256 + threadIdx.x;
    if (i >= n) return;
    deg[i] = 1.0f / sqrtf(deg[i]);   // deg >= 1 always
}

// batch is sorted: count of graph g = lower_bound(g+1) - lower_bound(g).
__global__ void k_gcnt(const int* __restrict__ batch, float* __restrict__ cntG, int n, int g)
{
    int t = threadIdx.x;
    if (t >= g) return;
    // lower_bound(batch, t) and lower_bound(batch, t+1)
    int lo0 = 0, hi0 = n;
    while (lo0 < hi0) { int m = (lo0 + hi0) >> 1; if (batch[m] < t) lo0 = m + 1; else hi0 = m; }
    int lo1 = lo0, hi1 = n;
    int t1 = t + 1;
    while (lo1 < hi1) { int m = (lo1 + hi1) >> 1; if (batch[m] < t1) lo1 = m + 1; else hi1 = m; }
    cntG[t] = (float)(lo1 - lo0);
}

// ---- exclusive scan of cntN[0..n) into start[0..n), 1024 elems/block -------
__global__ __launch_bounds__(256) void k_scan1(const int* __restrict__ cnt, int* __restrict__ start,
                                               int* __restrict__ partials, int n)
{
    __shared__ int s[256];
    int t = threadIdx.x;
    int base = blockIdx.x * 1024 + t * 4;
    int v[4];
#pragma unroll
    for (int j = 0; j < 4; ++j) { int idx = base + j; v[j] = (idx < n) ? cnt[idx] : 0; }
    int tsum = v[0] + v[1] + v[2] + v[3];
    s[t] = tsum; __syncthreads();
    for (int off = 1; off < 256; off <<= 1) {
        int xv = (t >= off) ? s[t - off] : 0;
        __syncthreads();
        s[t] += xv;
        __syncthreads();
    }
    if (t == 255) partials[blockIdx.x] = s[255];
    int run = s[t] - tsum;  // exclusive prefix of this thread
#pragma unroll
    for (int j = 0; j < 4; ++j) { int idx = base + j; if (idx < n) start[idx] = run; run += v[j]; }
}

__global__ __launch_bounds__(256) void k_scan2(int* partials, int nb)
{
    __shared__ int s[256];
    int t = threadIdx.x;
    int offset = 0;
    for (int b0 = 0; b0 < nb; b0 += 256) {
        int v = (b0 + t < nb) ? partials[b0 + t] : 0;
        s[t] = v; __syncthreads();
        for (int off = 1; off < 256; off <<= 1) {
            int xv = (t >= off) ? s[t - off] : 0;
            __syncthreads();
            s[t] += xv;
            __syncthreads();
        }
        int excl = s[t] - v;
        int tot = s[255];
        if (b0 + t < nb) partials[b0 + t] = offset + excl;
        offset += tot;
        __syncthreads();
    }
}

__global__ __launch_bounds__(256) void k_scan3(int* __restrict__ start, int* __restrict__ pos,
                                               const int* __restrict__ partials, int n, int total)
{
    int i = blockIdx.x * 256 + threadIdx.x;
    if (i < n) {
        int v = start[i] + partials[i >> 10];
        start[i] = v;
        pos[i] = v;
    }
    if (i == 0) start[n] = total;
}

__global__ __launch_bounds__(256) void k_fill(const int* __restrict__ ei, const float* __restrict__ ew,
                                              const float* __restrict__ dinv, int* pos,
                                              int* __restrict__ csrc, float* __restrict__ cw, int e)
{
    int i = blockIdx.x * 256 + threadIdx.x;
    if (i >= e) return;
    int r = ei[i], c = ei[e + i];
    int idx = atomicAdd(&pos[c], 1);
    csrc[idx] = r;
    cw[idx]   = dinv[r] * ew[i] * dinv[c];
}

// ---- C[M,128] = A[M,128] @ W[128,128] (+bias)(+relu) -----------------------
// Block: 256 threads, 32 rows. W + x-tile staged in LDS (80 KiB -> 2 blk/CU).
// Thread micro-tile: 4 rows x 4 cols, cols strided by 32 (conflict-free b32).
__global__ __launch_bounds__(256, 2) void k_gemm(const float* __restrict__ A, const float* __restrict__ W,
                                                 const float* __restrict__ bias, float* __restrict__ C,
                                                 int relu, int M)
{
    __shared__ float sW[16384];
    __shared__ float sX[4096];
    int t = threadIdx.x;
    {
        const float4* W4 = (const float4*)W;
        float4* sW4 = (float4*)sW;
#pragma unroll
        for (int i = 0; i < 16; ++i) sW4[t + i * 256] = W4[t + i * 256];
    }
    int r0 = blockIdx.x * 32;
    {
        const float4* A4 = (const float4*)A;
        float4* sX4 = (float4*)sX;
#pragma unroll
        for (int i = 0; i < 4; ++i) {
            int idx = t + i * 256;       // float4 index in tile [0,1024)
            int rl = idx >> 5;           // local row (32 float4 per row)
            float4 v = make_float4(0.f, 0.f, 0.f, 0.f);
            if (r0 + rl < M) v = A4[(size_t)r0 * 32 + idx];
            sX4[idx] = v;
        }
    }
    __syncthreads();

    int tc = t & 31;   // column lane: cols {tc, tc+32, tc+64, tc+96}
    int tr = t >> 5;   // row group:   rows {tr*4 .. tr*4+3}
    float acc[4][4];
#pragma unroll
    for (int m = 0; m < 4; ++m)
#pragma unroll
        for (int nn = 0; nn < 4; ++nn) acc[m][nn] = 0.f;

#pragma unroll 4
    for (int k = 0; k < 128; ++k) {
        float b0 = sW[k * 128 + tc];
        float b1 = sW[k * 128 + tc + 32];
        float b2 = sW[k * 128 + tc + 64];
        float b3 = sW[k * 128 + tc + 96];
        float a0 = sX[(tr * 4 + 0) * 128 + k];
        float a1 = sX[(tr * 4 + 1) * 128 + k];
        float a2 = sX[(tr * 4 + 2) * 128 + k];
        float a3 = sX[(tr * 4 + 3) * 128 + k];
        acc[0][0] = fmaf(a0, b0, acc[0][0]); acc[0][1] = fmaf(a0, b1, acc[0][1]);
        acc[0][2] = fmaf(a0, b2, acc[0][2]); acc[0][3] = fmaf(a0, b3, acc[0][3]);
        acc[1][0] = fmaf(a1, b0, acc[1][0]); acc[1][1] = fmaf(a1, b1, acc[1][1]);
        acc[1][2] = fmaf(a1, b2, acc[1][2]); acc[1][3] = fmaf(a1, b3, acc[1][3]);
        acc[2][0] = fmaf(a2, b0, acc[2][0]); acc[2][1] = fmaf(a2, b1, acc[2][1]);
        acc[2][2] = fmaf(a2, b2, acc[2][2]); acc[2][3] = fmaf(a2, b3, acc[2][3]);
        acc[3][0] = fmaf(a3, b0, acc[3][0]); acc[3][1] = fmaf(a3, b1, acc[3][1]);
        acc[3][2] = fmaf(a3, b2, acc[3][2]); acc[3][3] = fmaf(a3, b3, acc[3][3]);
    }

#pragma unroll
    for (int m = 0; m < 4; ++m) {
        int row = r0 + tr * 4 + m;
        if (row >= M) continue;
#pragma unroll
        for (int nn = 0; nn < 4; ++nn) {
            int col = tc + nn * 32;
            float v = acc[m][nn];
            if (bias) v += bias[col];
            if (relu) v = fmaxf(v, 0.f);
            C[(size_t)row * 128 + col] = v;
        }
    }
}

// ---- pull aggregation: one wave per dst node, float2 per lane --------------
__global__ __launch_bounds__(256) void k_agg(const float* __restrict__ xw, const int* __restrict__ start,
                                             const int* __restrict__ csrc, const float* __restrict__ cw,
                                             const float* __restrict__ dinv, const float* __restrict__ bias,
                                             float* __restrict__ hout, int n)
{
    int wid  = (blockIdx.x * 256 + threadIdx.x) >> 6;
    int lane = threadIdx.x & 63;
    if (wid >= n) return;
    const float2* xw2 = (const float2*)xw;
    float di = dinv[wid];
    float sn = di * di;                       // self-loop norm
    float2 v = xw2[(size_t)wid * 64 + lane];
    float ax = v.x * sn, ay = v.y * sn;
    int s0 = start[wid], s1 = start[wid + 1];
    for (int j = s0; j < s1; ++j) {
        int s = csrc[j];
        float w = cw[j];
        float2 u = xw2[(size_t)s * 64 + lane];
        ax = fmaf(w, u.x, ax);
        ay = fmaf(w, u.y, ay);
    }
    ax = fmaxf(ax + bias[lane * 2], 0.f);
    ay = fmaxf(ay + bias[lane * 2 + 1], 0.f);
    float2 r; r.x = ax; r.y = ay;
    ((float2*)hout)[(size_t)wid * 64 + lane] = r;
}

// ---- pooling: run-based pre-reduction over sorted batch, atomic flush ------
// h >= 0 (post-relu) => float atomicMax via uint punning is order-correct.
__global__ __launch_bounds__(256) void k_pool(const float* __restrict__ h, const int* __restrict__ batch,
                                              float* gmax, float* gsum, int n)
{
    int c = threadIdx.x & 127, sub = threadIdx.x >> 7;
    int r0 = blockIdx.x * 128;
    int rend = min(r0 + 128, n);
    float mx = 0.f, sm = 0.f;
    int cur = -1;
    for (int r = r0 + sub; r < rend; r += 2) {
        int b = batch[r];
        if (b != cur) {
            if (cur >= 0) {
                atomicMax((unsigned int*)&gmax[cur * 128 + c], __float_as_uint(mx));
                atomicAdd(&gsum[cur * 128 + c], sm);
            }
            cur = b; mx = 0.f; sm = 0.f;
        }
        float v = h[(size_t)r * 128 + c];
        mx = fmaxf(mx, v);
        sm += v;
    }
    if (cur >= 0) {
        atomicMax((unsigned int*)&gmax[cur * 128 + c], __float_as_uint(mx));
        atomicAdd(&gsum[cur * 128 + c], sm);
    }
}

__global__ __launch_bounds__(256) void k_final(const float* __restrict__ gmax, const float* __restrict__ gsum,
                                               const float* __restrict__ cntG, float* __restrict__ out,
                                               int G, int L)
{
    int i = blockIdx.x * 256 + threadIdx.x;
    int tot = L * G * 128;
    if (i >= tot) return;
    int c = i & 127;
    int g = (i >> 7) % G;
    int l = i / (G * 128);
    float ct = fmaxf(cntG[g], 1.0f);
    out[(size_t)g * (L * 256) + l * 256 + c]       = gmax[i];
    out[(size_t)g * (L * 256) + l * 256 + 128 + c] = gsum[i] / ct;
}

static inline int divup(int a, int b) { return (a + b - 1) / b; }

extern "C" void kernel_launch(void* const* d_in, const int* in_sizes, int n_in,
                              void* d_out, int out_size, void* d_ws, size_t ws_size,
                              hipStream_t stream)
{
    const float* x     = (const float*)d_in[0];
    const float* ew    = (const float*)d_in[1];
    const float* W1    = (const float*)d_in[2];
    const float* b1    = (const float*)d_in[3];
    const float* W2    = (const float*)d_in[4];
    const float* b2    = (const float*)d_in[5];
    const float* cW    = (const float*)d_in[6];
    const float* cB    = (const float*)d_in[7];
    const int*   ei    = (const int*)d_in[8];
    const int*   batch = (const int*)d_in[9];
    float* out = (float*)d_out;

    const int E = in_sizes[1];
    const int N = in_sizes[9];
    const int L = in_sizes[7] / 128;
    const int G = out_size / (L * 256);

    char* p = (char*)d_ws;
    auto carve = [&](size_t bytes) -> void* {
        void* q = (void*)p;
        p += (bytes + 255) & ~(size_t)255;
        return q;
    };
    float* dinv     = (float*)carve((size_t)N * 4);        // deg, then 1/sqrt in place
    int*   cntN     = (int*)  carve((size_t)N * 4);
    int*   start    = (int*)  carve((size_t)(N + 1) * 4);
    int*   pos      = (int*)  carve((size_t)N * 4);
    int*   partials = (int*)  carve(4096);
    int*   csrc     = (int*)  carve((size_t)E * 4);
    float* cw       = (float*)carve((size_t)E * 4);
    float* gmax     = (float*)carve((size_t)L * G * 128 * 4);
    float* gsum     = (float*)carve((size_t)L * G * 128 * 4);
    float* cntG     = (float*)carve((size_t)G * 4);
    float* bufA     = (float*)carve((size_t)N * 128 * 4);
    float* bufB     = (float*)carve((size_t)N * 128 * 4);

    const int npool = L * G * 128;

    // --- preprocessing -----------------------------------------------------
    {
        int mx = N > npool ? N : npool;
        k_init<<<divup(mx, 256), 256, 0, stream>>>(dinv, cntN, gmax, gsum, N, npool);
    }
    k_edge_scatter<<<divup(E, 256), 256, 0, stream>>>(ei, ew, dinv, cntN, E);
    k_dinv<<<divup(N, 256), 256, 0, stream>>>(dinv, N);
    k_gcnt<<<1, 64, 0, stream>>>(batch, cntG, N, G);

    int nb1 = divup(N, 1024);
    k_scan1<<<nb1, 256, 0, stream>>>(cntN, start, partials, N);
    k_scan2<<<1, 256, 0, stream>>>(partials, nb1);
    k_scan3<<<divup(N, 256), 256, 0, stream>>>(start, pos, partials, N, E);
    k_fill<<<divup(E, 256), 256, 0, stream>>>(ei, ew, dinv, pos, csrc, cw, E);

    // --- dense encoder -----------------------------------------------------
    int gblocks = divup(N, 32);
    k_gemm<<<gblocks, 256, 0, stream>>>(x,    W1, b1, bufA, 1, N);
    k_gemm<<<gblocks, 256, 0, stream>>>(bufA, W2, b2, bufB, 1, N);

    // --- conv layers + pooling --------------------------------------------
    int ablocks = divup(N, 4);
    int pblocks = divup(N, 128);
    for (int l = 0; l < L; ++l) {
        k_gemm<<<gblocks, 256, 0, stream>>>(bufB, cW + (size_t)l * 128 * 128, nullptr, bufA, 0, N);
        k_agg<<<ablocks, 256, 0, stream>>>(bufA, start, csrc, cw, dinv, cB + (size_t)l * 128, bufB, N);
        k_pool<<<pblocks, 256, 0, stream>>>(bufB, batch, gmax + (size_t)l * G * 128, gsum + (size_t)l * G * 128, N);
    }

    k_final<<<divup(L * G * 128, 256), 256, 0, stream>>>(gmax, gsum, cntG, out, G, L);
}

// Round 3
// 908.760 us; speedup vs baseline: 1.9929x; 1.2952x over previous
//
#include <hip/hip_runtime.h>

// ---------------------------------------------------------------------------
// CustomGCN: 2 dense layers + 3 GCNConv layers + per-layer (max||mean) pool.
// R1: binary-search cntG (removed 634us atomic wall).
// R2: bf16 hidden pipeline. MFMA bf16 GEMMs (weights pre-linearized into
//     fragment order), bf16 gather table for agg (halves the 406MB fetch),
//     bf16 pooling input. All accumulation in f32.
// ---------------------------------------------------------------------------

typedef __attribute__((ext_vector_type(8))) short bf16x8;
typedef __attribute__((ext_vector_type(4))) float f32x4;

__device__ __forceinline__ unsigned short f2b(float f) {  // RNE f32->bf16
    unsigned int u = __float_as_uint(f);
    return (unsigned short)((u + 0x7fffu + ((u >> 16) & 1u)) >> 16);
}
__device__ __forceinline__ float b2f(unsigned short h) {
    return __uint_as_float((unsigned int)h << 16);
}

// ---------------- preprocessing --------------------------------------------
__global__ __launch_bounds__(256) void k_init(float* __restrict__ deg, int* __restrict__ cntN,
                                              float* __restrict__ gmax, float* __restrict__ gsum,
                                              int n, int npool)
{
    int i = blockIdx.x * 256 + threadIdx.x;
    if (i < n) { deg[i] = 1.0f; cntN[i] = 0; }
    if (i < npool) { gmax[i] = 0.0f; gsum[i] = 0.0f; }
}

__global__ __launch_bounds__(256) void k_edge_scatter(const int* __restrict__ ei,
                                                      const float* __restrict__ ew,
                                                      float* deg, int* cntN, int e)
{
    int i = blockIdx.x * 256 + threadIdx.x;
    if (i >= e) return;
    int c = ei[e + i];
    atomicAdd(&deg[c], ew[i]);
    atomicAdd(&cntN[c], 1);
}

__global__ __launch_bounds__(256) void k_dinv(float* deg, int n)
{
    int i = blockIdx.x * 256 + threadIdx.x;
    if (i >= n) return;
    deg[i] = 1.0f / sqrtf(deg[i]);
}

__global__ void k_gcnt(const int* __restrict__ batch, float* __restrict__ cntG, int n, int g)
{
    int t = threadIdx.x;
    if (t >= g) return;
    int lo0 = 0, hi0 = n;
    while (lo0 < hi0) { int m = (lo0 + hi0) >> 1; if (batch[m] < t) lo0 = m + 1; else hi0 = m; }
    int lo1 = lo0, hi1 = n, t1 = t + 1;
    while (lo1 < hi1) { int m = (lo1 + hi1) >> 1; if (batch[m] < t1) lo1 = m + 1; else hi1 = m; }
    cntG[t] = (float)(lo1 - lo0);
}

__global__ __launch_bounds__(256) void k_scan1(const int* __restrict__ cnt, int* __restrict__ start,
                                               int* __restrict__ partials, int n)
{
    __shared__ int s[256];
    int t = threadIdx.x;
    int base = blockIdx.x * 1024 + t * 4;
    int v[4];
#pragma unroll
    for (int j = 0; j < 4; ++j) { int idx = base + j; v[j] = (idx < n) ? cnt[idx] : 0; }
    int tsum = v[0] + v[1] + v[2] + v[3];
    s[t] = tsum; __syncthreads();
    for (int off = 1; off < 256; off <<= 1) {
        int xv = (t >= off) ? s[t - off] : 0;
        __syncthreads();
        s[t] += xv;
        __syncthreads();
    }
    if (t == 255) partials[blockIdx.x] = s[255];
    int run = s[t] - tsum;
#pragma unroll
    for (int j = 0; j < 4; ++j) { int idx = base + j; if (idx < n) start[idx] = run; run += v[j]; }
}

__global__ __launch_bounds__(256) void k_scan2(int* partials, int nb)
{
    __shared__ int s[256];
    int t = threadIdx.x;
    int offset = 0;
    for (int b0 = 0; b0 < nb; b0 += 256) {
        int v = (b0 + t < nb) ? partials[b0 + t] : 0;
        s[t] = v; __syncthreads();
        for (int off = 1; off < 256; off <<= 1) {
            int xv = (t >= off) ? s[t - off] : 0;
            __syncthreads();
            s[t] += xv;
            __syncthreads();
        }
        int excl = s[t] - v;
        int tot = s[255];
        if (b0 + t < nb) partials[b0 + t] = offset + excl;
        offset += tot;
        __syncthreads();
    }
}

__global__ __launch_bounds__(256) void k_scan3(int* __restrict__ start, int* __restrict__ pos,
                                               const int* __restrict__ partials, int n, int total)
{
    int i = blockIdx.x * 256 + threadIdx.x;
    if (i < n) {
        int v = start[i] + partials[i >> 10];
        start[i] = v;
        pos[i] = v;
    }
    if (i == 0) start[n] = total;
}

__global__ __launch_bounds__(256) void k_fill(const int* __restrict__ ei, const float* __restrict__ ew,
                                              const float* __restrict__ dinv, int* pos,
                                              int* __restrict__ csrc, float* __restrict__ cw, int e)
{
    int i = blockIdx.x * 256 + threadIdx.x;
    if (i >= e) return;
    int r = ei[i], c = ei[e + i];
    int idx = atomicAdd(&pos[c], 1);
    csrc[idx] = r;
    cw[idx]   = dinv[r] * ew[i] * dinv[c];
}

// ---------------- weight linearization into MFMA fragment order ------------
// Wf[((ct*4+kt)*64 + lane)*8 + j] = bf16(W[kt*32 + 8*(lane>>4) + j][ct*16 + (lane&15)])
__global__ __launch_bounds__(256) void k_wfrag(const float* __restrict__ W, unsigned short* __restrict__ Wf)
{
    int idx = blockIdx.x * 256 + threadIdx.x;   // [0, 2048)
    if (idx >= 2048) return;
    int ctkt = idx >> 6, lane = idx & 63;
    int kt = ctkt & 3, ct = ctkt >> 2;
    int k0 = kt * 32 + (lane >> 4) * 8;
    int col = ct * 16 + (lane & 15);
    bf16x8 v;
#pragma unroll
    for (int j = 0; j < 8; ++j) v[j] = (short)f2b(W[(k0 + j) * 128 + col]);
    *(bf16x8*)&Wf[(size_t)idx * 8] = v;
}

// ---------------- MFMA GEMM: C[M,128] = A[M,128] @ W[128,128] --------------
// 256 thr = 4 waves, each wave one 16-row strip. A bf16 (or f32 via Af32).
// B frags from L1-resident linearized Wf. f32 accum, bf16 store.
__global__ __launch_bounds__(256) void k_gemm_mf(const unsigned short* __restrict__ A,
                                                 const float* __restrict__ Af32,
                                                 const unsigned short* __restrict__ Wf,
                                                 const float* __restrict__ bias,
                                                 unsigned short* __restrict__ C,
                                                 int relu, int M)
{
    int t = threadIdx.x;
    int lane = t & 63, w = t >> 6;
    int s = blockIdx.x * 4 + w;
    if (s * 16 >= M) return;
    int r0 = s * 16;
    int row = r0 + (lane & 15);
    int k0 = (lane >> 4) * 8;

    bf16x8 af[4];
    if (A) {
#pragma unroll
        for (int kt = 0; kt < 4; ++kt) {
            bf16x8 a = {0,0,0,0,0,0,0,0};
            if (row < M) a = *(const bf16x8*)&A[(size_t)row * 128 + k0 + kt * 32];
            af[kt] = a;
        }
    } else {
#pragma unroll
        for (int kt = 0; kt < 4; ++kt) {
            bf16x8 a = {0,0,0,0,0,0,0,0};
            if (row < M) {
                const float4* A4 = (const float4*)(Af32 + (size_t)row * 128 + k0 + kt * 32);
                float4 p = A4[0], q = A4[1];
                a[0] = (short)f2b(p.x); a[1] = (short)f2b(p.y);
                a[2] = (short)f2b(p.z); a[3] = (short)f2b(p.w);
                a[4] = (short)f2b(q.x); a[5] = (short)f2b(q.y);
                a[6] = (short)f2b(q.z); a[7] = (short)f2b(q.w);
            }
            af[kt] = a;
        }
    }

    int orow = r0 + 4 * (lane >> 4);
    int ocol = lane & 15;
#pragma unroll
    for (int ct = 0; ct < 8; ++ct) {
        f32x4 acc = {0.f, 0.f, 0.f, 0.f};
#pragma unroll
        for (int kt = 0; kt < 4; ++kt) {
            bf16x8 b = *(const bf16x8*)&Wf[(size_t)(((ct << 2) | kt) * 64 + lane) * 8];
            acc = __builtin_amdgcn_mfma_f32_16x16x32_bf16(af[kt], b, acc, 0, 0, 0);
        }
        float bv = bias ? bias[ct * 16 + ocol] : 0.f;
#pragma unroll
        for (int j = 0; j < 4; ++j) {
            int rr = orow + j;
            if (rr < M) {
                float v = acc[j] + bv;
                if (relu) v = fmaxf(v, 0.f);
                C[(size_t)rr * 128 + ct * 16 + ocol] = f2b(v);
            }
        }
    }
}

// ---------------- pull aggregation (bf16 gather, f32 accum, bf16 out) ------
__global__ __launch_bounds__(256) void k_agg(const unsigned int* __restrict__ xw,
                                             const int* __restrict__ start,
                                             const int* __restrict__ csrc, const float* __restrict__ cw,
                                             const float* __restrict__ dinv, const float* __restrict__ bias,
                                             unsigned int* __restrict__ hout, int n)
{
    int wid  = (blockIdx.x * 256 + threadIdx.x) >> 6;
    int lane = threadIdx.x & 63;
    if (wid >= n) return;
    float di = dinv[wid];
    float sn = di * di;
    unsigned int v = xw[(size_t)wid * 64 + lane];
    float ax = __uint_as_float(v << 16) * sn;
    float ay = __uint_as_float(v & 0xffff0000u) * sn;
    int s0 = start[wid], s1 = start[wid + 1];
    for (int j = s0; j < s1; ++j) {
        int s = csrc[j];
        float w = cw[j];
        unsigned int u = xw[(size_t)s * 64 + lane];
        ax = fmaf(w, __uint_as_float(u << 16), ax);
        ay = fmaf(w, __uint_as_float(u & 0xffff0000u), ay);
    }
    ax = fmaxf(ax + bias[lane * 2], 0.f);
    ay = fmaxf(ay + bias[lane * 2 + 1], 0.f);
    hout[(size_t)wid * 64 + lane] = (unsigned int)f2b(ax) | ((unsigned int)f2b(ay) << 16);
}

// ---------------- pooling (bf16 in) ----------------------------------------
__global__ __launch_bounds__(256) void k_pool(const unsigned short* __restrict__ h,
                                              const int* __restrict__ batch,
                                              float* gmax, float* gsum, int n)
{
    int c = threadIdx.x & 127, sub = threadIdx.x >> 7;
    int r0 = blockIdx.x * 128;
    int rend = min(r0 + 128, n);
    float mx = 0.f, sm = 0.f;
    int cur = -1;
    for (int r = r0 + sub; r < rend; r += 2) {
        int b = batch[r];
        if (b != cur) {
            if (cur >= 0) {
                atomicMax((unsigned int*)&gmax[cur * 128 + c], __float_as_uint(mx));
                atomicAdd(&gsum[cur * 128 + c], sm);
            }
            cur = b; mx = 0.f; sm = 0.f;
        }
        float v = b2f(h[(size_t)r * 128 + c]);
        mx = fmaxf(mx, v);
        sm += v;
    }
    if (cur >= 0) {
        atomicMax((unsigned int*)&gmax[cur * 128 + c], __float_as_uint(mx));
        atomicAdd(&gsum[cur * 128 + c], sm);
    }
}

__global__ __launch_bounds__(256) void k_final(const float* __restrict__ gmax, const float* __restrict__ gsum,
                                               const float* __restrict__ cntG, float* __restrict__ out,
                                               int G, int L)
{
    int i = blockIdx.x * 256 + threadIdx.x;
    int tot = L * G * 128;
    if (i >= tot) return;
    int c = i & 127;
    int g = (i >> 7) % G;
    int l = i / (G * 128);
    float ct = fmaxf(cntG[g], 1.0f);
    out[(size_t)g * (L * 256) + l * 256 + c]       = gmax[i];
    out[(size_t)g * (L * 256) + l * 256 + 128 + c] = gsum[i] / ct;
}

static inline int divup(int a, int b) { return (a + b - 1) / b; }

extern "C" void kernel_launch(void* const* d_in, const int* in_sizes, int n_in,
                              void* d_out, int out_size, void* d_ws, size_t ws_size,
                              hipStream_t stream)
{
    const float* x     = (const float*)d_in[0];
    const float* ew    = (const float*)d_in[1];
    const float* W1    = (const float*)d_in[2];
    const float* b1    = (const float*)d_in[3];
    const float* W2    = (const float*)d_in[4];
    const float* b2    = (const float*)d_in[5];
    const float* cW    = (const float*)d_in[6];
    const float* cB    = (const float*)d_in[7];
    const int*   ei    = (const int*)d_in[8];
    const int*   batch = (const int*)d_in[9];
    float* out = (float*)d_out;

    const int E = in_sizes[1];
    const int N = in_sizes[9];
    const int L = in_sizes[7] / 128;
    const int G = out_size / (L * 256);

    char* p = (char*)d_ws;
    auto carve = [&](size_t bytes) -> void* {
        void* q = (void*)p;
        p += (bytes + 255) & ~(size_t)255;
        return q;
    };
    float* dinv     = (float*)carve((size_t)N * 4);
    int*   cntN     = (int*)  carve((size_t)N * 4);
    int*   start    = (int*)  carve((size_t)(N + 1) * 4);
    int*   pos      = (int*)  carve((size_t)N * 4);
    int*   partials = (int*)  carve(4096);
    int*   csrc     = (int*)  carve((size_t)E * 4);
    float* cw       = (float*)carve((size_t)E * 4);
    float* gmax     = (float*)carve((size_t)L * G * 128 * 4);
    float* gsum     = (float*)carve((size_t)L * G * 128 * 4);
    float* cntG     = (float*)carve((size_t)G * 4);
    unsigned short* wf[5];
    for (int i = 0; i < 5; ++i) wf[i] = (unsigned short*)carve(16384 * 2);
    unsigned short* xwb = (unsigned short*)carve((size_t)N * 128 * 2);
    unsigned short* hbA = (unsigned short*)carve((size_t)N * 128 * 2);
    unsigned short* hbB = (unsigned short*)carve((size_t)N * 128 * 2);

    const int npool = L * G * 128;

    // --- preprocessing -----------------------------------------------------
    {
        int mx = N > npool ? N : npool;
        k_init<<<divup(mx, 256), 256, 0, stream>>>(dinv, cntN, gmax, gsum, N, npool);
    }
    k_edge_scatter<<<divup(E, 256), 256, 0, stream>>>(ei, ew, dinv, cntN, E);
    k_dinv<<<divup(N, 256), 256, 0, stream>>>(dinv, N);
    k_gcnt<<<1, 64, 0, stream>>>(batch, cntG, N, G);

    int nb1 = divup(N, 1024);
    k_scan1<<<nb1, 256, 0, stream>>>(cntN, start, partials, N);
    k_scan2<<<1, 256, 0, stream>>>(partials, nb1);
    k_scan3<<<divup(N, 256), 256, 0, stream>>>(start, pos, partials, N, E);
    k_fill<<<divup(E, 256), 256, 0, stream>>>(ei, ew, dinv, pos, csrc, cw, E);

    // --- weight fragment linearization ------------------------------------
    k_wfrag<<<8, 256, 0, stream>>>(W1, wf[0]);
    k_wfrag<<<8, 256, 0, stream>>>(W2, wf[1]);
    for (int l = 0; l < L && l < 3; ++l)
        k_wfrag<<<8, 256, 0, stream>>>(cW + (size_t)l * 16384, wf[2 + l]);

    // --- dense encoder -----------------------------------------------------
    int gblocks = divup(N, 64);
    k_gemm_mf<<<gblocks, 256, 0, stream>>>(nullptr, x, wf[0], b1, hbA, 1, N);
    k_gemm_mf<<<gblocks, 256, 0, stream>>>(hbA, nullptr, wf[1], b2, hbB, 1, N);

    // --- conv layers + pooling --------------------------------------------
    int ablocks = divup(N, 4);
    int pblocks = divup(N, 128);
    unsigned short* cur = hbB;
    unsigned short* alt = hbA;
    for (int l = 0; l < L; ++l) {
        k_gemm_mf<<<gblocks, 256, 0, stream>>>(cur, nullptr, wf[2 + (l < 3 ? l : 2)], nullptr, xwb, 0, N);
        k_agg<<<ablocks, 256, 0, stream>>>((const unsigned int*)xwb, start, csrc, cw, dinv,
                                           cB + (size_t)l * 128, (unsigned int*)alt, N);
        k_pool<<<pblocks, 256, 0, stream>>>(alt, batch, gmax + (size_t)l * G * 128,
                                            gsum + (size_t)l * G * 128, N);
        unsigned short* tmp = cur; cur = alt; alt = tmp;
    }

    k_final<<<divup(L * G * 128, 256), 256, 0, stream>>>(gmax, gsum, cntG, out, G, L);
}

// Round 4
// 684.744 us; speedup vs baseline: 2.6448x; 1.3272x over previous
//
#include <hip/hip_runtime.h>

// ---------------------------------------------------------------------------
// CustomGCN: 2 dense layers + 3 GCNConv layers + per-layer (max||mean) pool.
// R1: binary-search cntG (removed 634us atomic wall).
// R2: bf16 hidden pipeline; MFMA bf16 GEMMs; bf16 gather table.
// R3: k_agg 8-deep software pipeline (8 outstanding gathers/wave) — was
//     latency-bound at 1.45 TB/s with a 1-deep dependent chain.
// ---------------------------------------------------------------------------

typedef __attribute__((ext_vector_type(8))) short bf16x8;
typedef __attribute__((ext_vector_type(4))) float f32x4;

__device__ __forceinline__ unsigned short f2b(float f) {  // RNE f32->bf16
    unsigned int u = __float_as_uint(f);
    return (unsigned short)((u + 0x7fffu + ((u >> 16) & 1u)) >> 16);
}
__device__ __forceinline__ float b2f(unsigned short h) {
    return __uint_as_float((unsigned int)h << 16);
}

// ---------------- preprocessing --------------------------------------------
__global__ __launch_bounds__(256) void k_init(float* __restrict__ deg, int* __restrict__ cntN,
                                              float* __restrict__ gmax, float* __restrict__ gsum,
                                              int n, int npool)
{
    int i = blockIdx.x * 256 + threadIdx.x;
    if (i < n) { deg[i] = 1.0f; cntN[i] = 0; }
    if (i < npool) { gmax[i] = 0.0f; gsum[i] = 0.0f; }
}

__global__ __launch_bounds__(256) void k_edge_scatter(const int* __restrict__ ei,
                                                      const float* __restrict__ ew,
                                                      float* deg, int* cntN, int e)
{
    int i = blockIdx.x * 256 + threadIdx.x;
    if (i >= e) return;
    int c = ei[e + i];
    atomicAdd(&deg[c], ew[i]);
    atomicAdd(&cntN[c], 1);
}

__global__ __launch_bounds__(256) void k_dinv(float* deg, int n)
{
    int i = blockIdx.x * 256 + threadIdx.x;
    if (i >= n) return;
    deg[i] = 1.0f / sqrtf(deg[i]);
}

__global__ void k_gcnt(const int* __restrict__ batch, float* __restrict__ cntG, int n, int g)
{
    int t = threadIdx.x;
    if (t >= g) return;
    int lo0 = 0, hi0 = n;
    while (lo0 < hi0) { int m = (lo0 + hi0) >> 1; if (batch[m] < t) lo0 = m + 1; else hi0 = m; }
    int lo1 = lo0, hi1 = n, t1 = t + 1;
    while (lo1 < hi1) { int m = (lo1 + hi1) >> 1; if (batch[m] < t1) lo1 = m + 1; else hi1 = m; }
    cntG[t] = (float)(lo1 - lo0);
}

__global__ __launch_bounds__(256) void k_scan1(const int* __restrict__ cnt, int* __restrict__ start,
                                               int* __restrict__ partials, int n)
{
    __shared__ int s[256];
    int t = threadIdx.x;
    int base = blockIdx.x * 1024 + t * 4;
    int v[4];
#pragma unroll
    for (int j = 0; j < 4; ++j) { int idx = base + j; v[j] = (idx < n) ? cnt[idx] : 0; }
    int tsum = v[0] + v[1] + v[2] + v[3];
    s[t] = tsum; __syncthreads();
    for (int off = 1; off < 256; off <<= 1) {
        int xv = (t >= off) ? s[t - off] : 0;
        __syncthreads();
        s[t] += xv;
        __syncthreads();
    }
    if (t == 255) partials[blockIdx.x] = s[255];
    int run = s[t] - tsum;
#pragma unroll
    for (int j = 0; j < 4; ++j) { int idx = base + j; if (idx < n) start[idx] = run; run += v[j]; }
}

__global__ __launch_bounds__(256) void k_scan2(int* partials, int nb)
{
    __shared__ int s[256];
    int t = threadIdx.x;
    int offset = 0;
    for (int b0 = 0; b0 < nb; b0 += 256) {
        int v = (b0 + t < nb) ? partials[b0 + t] : 0;
        s[t] = v; __syncthreads();
        for (int off = 1; off < 256; off <<= 1) {
            int xv = (t >= off) ? s[t - off] : 0;
            __syncthreads();
            s[t] += xv;
            __syncthreads();
        }
        int excl = s[t] - v;
        int tot = s[255];
        if (b0 + t < nb) partials[b0 + t] = offset + excl;
        offset += tot;
        __syncthreads();
    }
}

__global__ __launch_bounds__(256) void k_scan3(int* __restrict__ start, int* __restrict__ pos,
                                               const int* __restrict__ partials, int n, int total)
{
    int i = blockIdx.x * 256 + threadIdx.x;
    if (i < n) {
        int v = start[i] + partials[i >> 10];
        start[i] = v;
        pos[i] = v;
    }
    if (i == 0) start[n] = total;
}

__global__ __launch_bounds__(256) void k_fill(const int* __restrict__ ei, const float* __restrict__ ew,
                                              const float* __restrict__ dinv, int* pos,
                                              int* __restrict__ csrc, float* __restrict__ cw, int e)
{
    int i = blockIdx.x * 256 + threadIdx.x;
    if (i >= e) return;
    int r = ei[i], c = ei[e + i];
    int idx = atomicAdd(&pos[c], 1);
    csrc[idx] = r;
    cw[idx]   = dinv[r] * ew[i] * dinv[c];
}

// ---------------- weight linearization into MFMA fragment order ------------
__global__ __launch_bounds__(256) void k_wfrag(const float* __restrict__ W, unsigned short* __restrict__ Wf)
{
    int idx = blockIdx.x * 256 + threadIdx.x;   // [0, 2048)
    if (idx >= 2048) return;
    int ctkt = idx >> 6, lane = idx & 63;
    int kt = ctkt & 3, ct = ctkt >> 2;
    int k0 = kt * 32 + (lane >> 4) * 8;
    int col = ct * 16 + (lane & 15);
    bf16x8 v;
#pragma unroll
    for (int j = 0; j < 8; ++j) v[j] = (short)f2b(W[(k0 + j) * 128 + col]);
    *(bf16x8*)&Wf[(size_t)idx * 8] = v;
}

// ---------------- MFMA GEMM: C[M,128] = A[M,128] @ W[128,128] --------------
__global__ __launch_bounds__(256) void k_gemm_mf(const unsigned short* __restrict__ A,
                                                 const float* __restrict__ Af32,
                                                 const unsigned short* __restrict__ Wf,
                                                 const float* __restrict__ bias,
                                                 unsigned short* __restrict__ C,
                                                 int relu, int M)
{
    int t = threadIdx.x;
    int lane = t & 63, w = t >> 6;
    int s = blockIdx.x * 4 + w;
    if (s * 16 >= M) return;
    int r0 = s * 16;
    int row = r0 + (lane & 15);
    int k0 = (lane >> 4) * 8;

    bf16x8 af[4];
    if (A) {
#pragma unroll
        for (int kt = 0; kt < 4; ++kt) {
            bf16x8 a = {0,0,0,0,0,0,0,0};
            if (row < M) a = *(const bf16x8*)&A[(size_t)row * 128 + k0 + kt * 32];
            af[kt] = a;
        }
    } else {
#pragma unroll
        for (int kt = 0; kt < 4; ++kt) {
            bf16x8 a = {0,0,0,0,0,0,0,0};
            if (row < M) {
                const float4* A4 = (const float4*)(Af32 + (size_t)row * 128 + k0 + kt * 32);
                float4 p = A4[0], q = A4[1];
                a[0] = (short)f2b(p.x); a[1] = (short)f2b(p.y);
                a[2] = (short)f2b(p.z); a[3] = (short)f2b(p.w);
                a[4] = (short)f2b(q.x); a[5] = (short)f2b(q.y);
                a[6] = (short)f2b(q.z); a[7] = (short)f2b(q.w);
            }
            af[kt] = a;
        }
    }

    int orow = r0 + 4 * (lane >> 4);
    int ocol = lane & 15;
#pragma unroll
    for (int ct = 0; ct < 8; ++ct) {
        f32x4 acc = {0.f, 0.f, 0.f, 0.f};
#pragma unroll
        for (int kt = 0; kt < 4; ++kt) {
            bf16x8 b = *(const bf16x8*)&Wf[(size_t)(((ct << 2) | kt) * 64 + lane) * 8];
            acc = __builtin_amdgcn_mfma_f32_16x16x32_bf16(af[kt], b, acc, 0, 0, 0);
        }
        float bv = bias ? bias[ct * 16 + ocol] : 0.f;
#pragma unroll
        for (int j = 0; j < 4; ++j) {
            int rr = orow + j;
            if (rr < M) {
                float v = acc[j] + bv;
                if (relu) v = fmaxf(v, 0.f);
                C[(size_t)rr * 128 + ct * 16 + ocol] = f2b(v);
            }
        }
    }
}

// ---------------- pull aggregation: 8-deep gather pipeline -----------------
// One wave per dst node; lane holds 2 features (u32 of 2 bf16). 8 outstanding
// row-gathers per wave to cover L2/HBM latency. f32 accum, bf16 out.
__global__ __launch_bounds__(256) void k_agg(const unsigned int* __restrict__ xw,
                                             const int* __restrict__ start,
                                             const int* __restrict__ csrc, const float* __restrict__ cw,
                                             const float* __restrict__ dinv, const float* __restrict__ bias,
                                             unsigned int* __restrict__ hout, int n)
{
    int wid  = (blockIdx.x * 256 + threadIdx.x) >> 6;
    int lane = threadIdx.x & 63;
    if (wid >= n) return;
    float di = dinv[wid];
    float sn = di * di;
    unsigned int v = xw[(size_t)wid * 64 + lane];
    float ax = __uint_as_float(v << 16) * sn;
    float ay = __uint_as_float(v & 0xffff0000u) * sn;
    int s0 = start[wid], s1 = start[wid + 1];

    int j = s0;
    for (; j + 8 <= s1; j += 8) {
        int   si[8];
        float wi[8];
#pragma unroll
        for (int q = 0; q < 8; ++q) { si[q] = csrc[j + q]; wi[q] = cw[j + q]; }
        unsigned int u[8];
#pragma unroll
        for (int q = 0; q < 8; ++q) u[q] = xw[(size_t)si[q] * 64 + lane];
#pragma unroll
        for (int q = 0; q < 8; ++q) {
            ax = fmaf(wi[q], __uint_as_float(u[q] << 16), ax);
            ay = fmaf(wi[q], __uint_as_float(u[q] & 0xffff0000u), ay);
        }
    }
    {
        int rem = s1 - j;
        int   si[8];
        float wi[8];
#pragma unroll
        for (int q = 0; q < 8; ++q) {
            int idx = j + q;
            bool ok = q < rem;
            si[q] = ok ? csrc[idx] : 0;
            wi[q] = ok ? cw[idx] : 0.f;
        }
        unsigned int u[8];
#pragma unroll
        for (int q = 0; q < 8; ++q) u[q] = (q < rem) ? xw[(size_t)si[q] * 64 + lane] : 0u;
#pragma unroll
        for (int q = 0; q < 8; ++q) {
            ax = fmaf(wi[q], __uint_as_float(u[q] << 16), ax);
            ay = fmaf(wi[q], __uint_as_float(u[q] & 0xffff0000u), ay);
        }
    }

    ax = fmaxf(ax + bias[lane * 2], 0.f);
    ay = fmaxf(ay + bias[lane * 2 + 1], 0.f);
    hout[(size_t)wid * 64 + lane] = (unsigned int)f2b(ax) | ((unsigned int)f2b(ay) << 16);
}

// ---------------- pooling (bf16 in) ----------------------------------------
__global__ __launch_bounds__(256) void k_pool(const unsigned short* __restrict__ h,
                                              const int* __restrict__ batch,
                                              float* gmax, float* gsum, int n)
{
    int c = threadIdx.x & 127, sub = threadIdx.x >> 7;
    int r0 = blockIdx.x * 128;
    int rend = min(r0 + 128, n);
    float mx = 0.f, sm = 0.f;
    int cur = -1;
    for (int r = r0 + sub; r < rend; r += 2) {
        int b = batch[r];
        if (b != cur) {
            if (cur >= 0) {
                atomicMax((unsigned int*)&gmax[cur * 128 + c], __float_as_uint(mx));
                atomicAdd(&gsum[cur * 128 + c], sm);
            }
            cur = b; mx = 0.f; sm = 0.f;
        }
        float v = b2f(h[(size_t)r * 128 + c]);
        mx = fmaxf(mx, v);
        sm += v;
    }
    if (cur >= 0) {
        atomicMax((unsigned int*)&gmax[cur * 128 + c], __float_as_uint(mx));
        atomicAdd(&gsum[cur * 128 + c], sm);
    }
}

__global__ __launch_bounds__(256) void k_final(const float* __restrict__ gmax, const float* __restrict__ gsum,
                                               const float* __restrict__ cntG, float* __restrict__ out,
                                               int G, int L)
{
    int i = blockIdx.x * 256 + threadIdx.x;
    int tot = L * G * 128;
    if (i >= tot) return;
    int c = i & 127;
    int g = (i >> 7) % G;
    int l = i / (G * 128);
    float ct = fmaxf(cntG[g], 1.0f);
    out[(size_t)g * (L * 256) + l * 256 + c]       = gmax[i];
    out[(size_t)g * (L * 256) + l * 256 + 128 + c] = gsum[i] / ct;
}

static inline int divup(int a, int b) { return (a + b - 1) / b; }

extern "C" void kernel_launch(void* const* d_in, const int* in_sizes, int n_in,
                              void* d_out, int out_size, void* d_ws, size_t ws_size,
                              hipStream_t stream)
{
    const float* x     = (const float*)d_in[0];
    const float* ew    = (const float*)d_in[1];
    const float* W1    = (const float*)d_in[2];
    const float* b1    = (const float*)d_in[3];
    const float* W2    = (const float*)d_in[4];
    const float* b2    = (const float*)d_in[5];
    const float* cW    = (const float*)d_in[6];
    const float* cB    = (const float*)d_in[7];
    const int*   ei    = (const int*)d_in[8];
    const int*   batch = (const int*)d_in[9];
    float* out = (float*)d_out;

    const int E = in_sizes[1];
    const int N = in_sizes[9];
    const int L = in_sizes[7] / 128;
    const int G = out_size / (L * 256);

    char* p = (char*)d_ws;
    auto carve = [&](size_t bytes) -> void* {
        void* q = (void*)p;
        p += (bytes + 255) & ~(size_t)255;
        return q;
    };
    float* dinv     = (float*)carve((size_t)N * 4);
    int*   cntN     = (int*)  carve((size_t)N * 4);
    int*   start    = (int*)  carve((size_t)(N + 1) * 4);
    int*   pos      = (int*)  carve((size_t)N * 4);
    int*   partials = (int*)  carve(4096);
    int*   csrc     = (int*)  carve((size_t)E * 4);
    float* cw       = (float*)carve((size_t)E * 4);
    float* gmax     = (float*)carve((size_t)L * G * 128 * 4);
    float* gsum     = (float*)carve((size_t)L * G * 128 * 4);
    float* cntG     = (float*)carve((size_t)G * 4);
    unsigned short* wf[5];
    for (int i = 0; i < 5; ++i) wf[i] = (unsigned short*)carve(16384 * 2);
    unsigned short* xwb = (unsigned short*)carve((size_t)N * 128 * 2);
    unsigned short* hbA = (unsigned short*)carve((size_t)N * 128 * 2);
    unsigned short* hbB = (unsigned short*)carve((size_t)N * 128 * 2);

    const int npool = L * G * 128;

    // --- preprocessing -----------------------------------------------------
    {
        int mx = N > npool ? N : npool;
        k_init<<<divup(mx, 256), 256, 0, stream>>>(dinv, cntN, gmax, gsum, N, npool);
    }
    k_edge_scatter<<<divup(E, 256), 256, 0, stream>>>(ei, ew, dinv, cntN, E);
    k_dinv<<<divup(N, 256), 256, 0, stream>>>(dinv, N);
    k_gcnt<<<1, 64, 0, stream>>>(batch, cntG, N, G);

    int nb1 = divup(N, 1024);
    k_scan1<<<nb1, 256, 0, stream>>>(cntN, start, partials, N);
    k_scan2<<<1, 256, 0, stream>>>(partials, nb1);
    k_scan3<<<divup(N, 256), 256, 0, stream>>>(start, pos, partials, N, E);
    k_fill<<<divup(E, 256), 256, 0, stream>>>(ei, ew, dinv, pos, csrc, cw, E);

    // --- weight fragment linearization ------------------------------------
    k_wfrag<<<8, 256, 0, stream>>>(W1, wf[0]);
    k_wfrag<<<8, 256, 0, stream>>>(W2, wf[1]);
    for (int l = 0; l < L && l < 3; ++l)
        k_wfrag<<<8, 256, 0, stream>>>(cW + (size_t)l * 16384, wf[2 + l]);

    // --- dense encoder -----------------------------------------------------
    int gblocks = divup(N, 64);
    k_gemm_mf<<<gblocks, 256, 0, stream>>>(nullptr, x, wf[0], b1, hbA, 1, N);
    k_gemm_mf<<<gblocks, 256, 0, stream>>>(hbA, nullptr, wf[1], b2, hbB, 1, N);

    // --- conv layers + pooling --------------------------------------------
    int ablocks = divup(N, 4);
    int pblocks = divup(N, 128);
    unsigned short* cur = hbB;
    unsigned short* alt = hbA;
    for (int l = 0; l < L; ++l) {
        k_gemm_mf<<<gblocks, 256, 0, stream>>>(cur, nullptr, wf[2 + (l < 3 ? l : 2)], nullptr, xwb, 0, N);
        k_agg<<<ablocks, 256, 0, stream>>>((const unsigned int*)xwb, start, csrc, cw, dinv,
                                           cB + (size_t)l * 128, (unsigned int*)alt, N);
        k_pool<<<pblocks, 256, 0, stream>>>(alt, batch, gmax + (size_t)l * G * 128,
                                            gsum + (size_t)l * G * 128, N);
        unsigned short* tmp = cur; cur = alt; alt = tmp;
    }

    k_final<<<divup(L * G * 128, 256), 256, 0, stream>>>(gmax, gsum, cntG, out, G, L);
}

// Round 5
// 543.184 us; speedup vs baseline: 3.3341x; 1.2606x over previous
//
#include <hip/hip_runtime.h>

// ---------------------------------------------------------------------------
// CustomGCN: 2 dense layers + 3 GCNConv layers + per-layer (max||mean) pool.
// R1: binary-search cntG (removed 634us atomic wall).
// R2: bf16 hidden pipeline; MFMA bf16 GEMMs; bf16 gather table.
// R3: k_agg 8-deep gather pipeline.
// R4: CSC build with ONE u64 atomic/edge: packed (count<<52 | w*2^32) atomic
//     returns slot index + accumulates degree; fill pass is atomic-free.
//     (was 3.2M + 1.6M memory-side atomics = ~220us, now 1.6M)
// ---------------------------------------------------------------------------

typedef __attribute__((ext_vector_type(8))) short bf16x8;
typedef __attribute__((ext_vector_type(4))) float f32x4;

#define FRACBITS 52
#define FRACMASK ((1ULL << FRACBITS) - 1ULL)

__device__ __forceinline__ unsigned short f2b(float f) {  // RNE f32->bf16
    unsigned int u = __float_as_uint(f);
    return (unsigned short)((u + 0x7fffu + ((u >> 16) & 1u)) >> 16);
}
__device__ __forceinline__ float b2f(unsigned short h) {
    return __uint_as_float((unsigned int)h << 16);
}

// ---------------- preprocessing --------------------------------------------
__global__ __launch_bounds__(256) void k_init(unsigned long long* __restrict__ pk,
                                              float* __restrict__ gmax, float* __restrict__ gsum,
                                              int n, int npool)
{
    int i = blockIdx.x * 256 + threadIdx.x;
    if (i < n) pk[i] = 0ULL;
    if (i < npool) { gmax[i] = 0.0f; gsum[i] = 0.0f; }
}

// one u64 atomic per edge: count in [52:63], weight-sum fixed-point in [0:51]
__global__ __launch_bounds__(256) void k_phase1(const int* __restrict__ ei,
                                                const float* __restrict__ ew,
                                                unsigned long long* pk,
                                                int* __restrict__ eslot, int e)
{
    int i = blockIdx.x * 256 + threadIdx.x;
    if (i >= e) return;
    int c = ei[e + i];
    float w = ew[i];
    unsigned long long fixed = (unsigned long long)((double)w * 4294967296.0);
    unsigned long long packed = (1ULL << FRACBITS) | fixed;
    unsigned long long old = atomicAdd(&pk[c], packed);
    eslot[i] = (int)(old >> FRACBITS);
}

__global__ __launch_bounds__(256) void k_dinv(const unsigned long long* __restrict__ pk,
                                              float* __restrict__ dinv, int n)
{
    int i = blockIdx.x * 256 + threadIdx.x;
    if (i >= n) return;
    float deg = 1.0f + (float)((double)(pk[i] & FRACMASK) * (1.0 / 4294967296.0));
    dinv[i] = 1.0f / sqrtf(deg);
}

__global__ void k_gcnt(const int* __restrict__ batch, float* __restrict__ cntG, int n, int g)
{
    int t = threadIdx.x;
    if (t >= g) return;
    int lo0 = 0, hi0 = n;
    while (lo0 < hi0) { int m = (lo0 + hi0) >> 1; if (batch[m] < t) lo0 = m + 1; else hi0 = m; }
    int lo1 = lo0, hi1 = n, t1 = t + 1;
    while (lo1 < hi1) { int m = (lo1 + hi1) >> 1; if (batch[m] < t1) lo1 = m + 1; else hi1 = m; }
    cntG[t] = (float)(lo1 - lo0);
}

// ---- exclusive scan of counts (pk>>52) into start[0..n) --------------------
__global__ __launch_bounds__(256) void k_scan1(const unsigned long long* __restrict__ pk,
                                               int* __restrict__ start,
                                               int* __restrict__ partials, int n)
{
    __shared__ int s[256];
    int t = threadIdx.x;
    int base = blockIdx.x * 1024 + t * 4;
    int v[4];
#pragma unroll
    for (int j = 0; j < 4; ++j) { int idx = base + j; v[j] = (idx < n) ? (int)(pk[idx] >> FRACBITS) : 0; }
    int tsum = v[0] + v[1] + v[2] + v[3];
    s[t] = tsum; __syncthreads();
    for (int off = 1; off < 256; off <<= 1) {
        int xv = (t >= off) ? s[t - off] : 0;
        __syncthreads();
        s[t] += xv;
        __syncthreads();
    }
    if (t == 255) partials[blockIdx.x] = s[255];
    int run = s[t] - tsum;
#pragma unroll
    for (int j = 0; j < 4; ++j) { int idx = base + j; if (idx < n) start[idx] = run; run += v[j]; }
}

__global__ __launch_bounds__(256) void k_scan2(int* partials, int nb)
{
    __shared__ int s[256];
    int t = threadIdx.x;
    int offset = 0;
    for (int b0 = 0; b0 < nb; b0 += 256) {
        int v = (b0 + t < nb) ? partials[b0 + t] : 0;
        s[t] = v; __syncthreads();
        for (int off = 1; off < 256; off <<= 1) {
            int xv = (t >= off) ? s[t - off] : 0;
            __syncthreads();
            s[t] += xv;
            __syncthreads();
        }
        int excl = s[t] - v;
        int tot = s[255];
        if (b0 + t < nb) partials[b0 + t] = offset + excl;
        offset += tot;
        __syncthreads();
    }
}

__global__ __launch_bounds__(256) void k_scan3(int* __restrict__ start,
                                               const int* __restrict__ partials, int n, int total)
{
    int i = blockIdx.x * 256 + threadIdx.x;
    if (i < n) start[i] += partials[i >> 10];
    if (i == 0) start[n] = total;
}

// ---- atomic-free fill: slot was allocated in phase1 ------------------------
__global__ __launch_bounds__(256) void k_phase2(const int* __restrict__ ei, const float* __restrict__ ew,
                                                const float* __restrict__ dinv,
                                                const int* __restrict__ start,
                                                const int* __restrict__ eslot,
                                                int* __restrict__ csrc, float* __restrict__ cw, int e)
{
    int i = blockIdx.x * 256 + threadIdx.x;
    if (i >= e) return;
    int r = ei[i], c = ei[e + i];
    int idx = start[c] + eslot[i];
    csrc[idx] = r;
    cw[idx]   = dinv[r] * ew[i] * dinv[c];
}

// ---------------- weight linearization into MFMA fragment order ------------
__global__ __launch_bounds__(256) void k_wfrag(const float* __restrict__ W, unsigned short* __restrict__ Wf)
{
    int idx = blockIdx.x * 256 + threadIdx.x;   // [0, 2048)
    if (idx >= 2048) return;
    int ctkt = idx >> 6, lane = idx & 63;
    int kt = ctkt & 3, ct = ctkt >> 2;
    int k0 = kt * 32 + (lane >> 4) * 8;
    int col = ct * 16 + (lane & 15);
    bf16x8 v;
#pragma unroll
    for (int j = 0; j < 8; ++j) v[j] = (short)f2b(W[(k0 + j) * 128 + col]);
    *(bf16x8*)&Wf[(size_t)idx * 8] = v;
}

// ---------------- MFMA GEMM: C[M,128] = A[M,128] @ W[128,128] --------------
__global__ __launch_bounds__(256) void k_gemm_mf(const unsigned short* __restrict__ A,
                                                 const float* __restrict__ Af32,
                                                 const unsigned short* __restrict__ Wf,
                                                 const float* __restrict__ bias,
                                                 unsigned short* __restrict__ C,
                                                 int relu, int M)
{
    int t = threadIdx.x;
    int lane = t & 63, w = t >> 6;
    int s = blockIdx.x * 4 + w;
    if (s * 16 >= M) return;
    int r0 = s * 16;
    int row = r0 + (lane & 15);
    int k0 = (lane >> 4) * 8;

    bf16x8 af[4];
    if (A) {
#pragma unroll
        for (int kt = 0; kt < 4; ++kt) {
            bf16x8 a = {0,0,0,0,0,0,0,0};
            if (row < M) a = *(const bf16x8*)&A[(size_t)row * 128 + k0 + kt * 32];
            af[kt] = a;
        }
    } else {
#pragma unroll
        for (int kt = 0; kt < 4; ++kt) {
            bf16x8 a = {0,0,0,0,0,0,0,0};
            if (row < M) {
                const float4* A4 = (const float4*)(Af32 + (size_t)row * 128 + k0 + kt * 32);
                float4 p = A4[0], q = A4[1];
                a[0] = (short)f2b(p.x); a[1] = (short)f2b(p.y);
                a[2] = (short)f2b(p.z); a[3] = (short)f2b(p.w);
                a[4] = (short)f2b(q.x); a[5] = (short)f2b(q.y);
                a[6] = (short)f2b(q.z); a[7] = (short)f2b(q.w);
            }
            af[kt] = a;
        }
    }

    int orow = r0 + 4 * (lane >> 4);
    int ocol = lane & 15;
#pragma unroll
    for (int ct = 0; ct < 8; ++ct) {
        f32x4 acc = {0.f, 0.f, 0.f, 0.f};
#pragma unroll
        for (int kt = 0; kt < 4; ++kt) {
            bf16x8 b = *(const bf16x8*)&Wf[(size_t)(((ct << 2) | kt) * 64 + lane) * 8];
            acc = __builtin_amdgcn_mfma_f32_16x16x32_bf16(af[kt], b, acc, 0, 0, 0);
        }
        float bv = bias ? bias[ct * 16 + ocol] : 0.f;
#pragma unroll
        for (int j = 0; j < 4; ++j) {
            int rr = orow + j;
            if (rr < M) {
                float v = acc[j] + bv;
                if (relu) v = fmaxf(v, 0.f);
                C[(size_t)rr * 128 + ct * 16 + ocol] = f2b(v);
            }
        }
    }
}

// ---------------- pull aggregation: 8-deep gather pipeline -----------------
__global__ __launch_bounds__(256) void k_agg(const unsigned int* __restrict__ xw,
                                             const int* __restrict__ start,
                                             const int* __restrict__ csrc, const float* __restrict__ cw,
                                             const float* __restrict__ dinv, const float* __restrict__ bias,
                                             unsigned int* __restrict__ hout, int n)
{
    int wid  = (blockIdx.x * 256 + threadIdx.x) >> 6;
    int lane = threadIdx.x & 63;
    if (wid >= n) return;
    float di = dinv[wid];
    float sn = di * di;
    unsigned int v = xw[(size_t)wid * 64 + lane];
    float ax = __uint_as_float(v << 16) * sn;
    float ay = __uint_as_float(v & 0xffff0000u) * sn;
    int s0 = start[wid], s1 = start[wid + 1];

    int j = s0;
    for (; j + 8 <= s1; j += 8) {
        int   si[8];
        float wi[8];
#pragma unroll
        for (int q = 0; q < 8; ++q) { si[q] = csrc[j + q]; wi[q] = cw[j + q]; }
        unsigned int u[8];
#pragma unroll
        for (int q = 0; q < 8; ++q) u[q] = xw[(size_t)si[q] * 64 + lane];
#pragma unroll
        for (int q = 0; q < 8; ++q) {
            ax = fmaf(wi[q], __uint_as_float(u[q] << 16), ax);
            ay = fmaf(wi[q], __uint_as_float(u[q] & 0xffff0000u), ay);
        }
    }
    {
        int rem = s1 - j;
        int   si[8];
        float wi[8];
#pragma unroll
        for (int q = 0; q < 8; ++q) {
            int idx = j + q;
            bool ok = q < rem;
            si[q] = ok ? csrc[idx] : 0;
            wi[q] = ok ? cw[idx] : 0.f;
        }
        unsigned int u[8];
#pragma unroll
        for (int q = 0; q < 8; ++q) u[q] = (q < rem) ? xw[(size_t)si[q] * 64 + lane] : 0u;
#pragma unroll
        for (int q = 0; q < 8; ++q) {
            ax = fmaf(wi[q], __uint_as_float(u[q] << 16), ax);
            ay = fmaf(wi[q], __uint_as_float(u[q] & 0xffff0000u), ay);
        }
    }

    ax = fmaxf(ax + bias[lane * 2], 0.f);
    ay = fmaxf(ay + bias[lane * 2 + 1], 0.f);
    hout[(size_t)wid * 64 + lane] = (unsigned int)f2b(ax) | ((unsigned int)f2b(ay) << 16);
}

// ---------------- pooling (bf16 in) ----------------------------------------
__global__ __launch_bounds__(256) void k_pool(const unsigned short* __restrict__ h,
                                              const int* __restrict__ batch,
                                              float* gmax, float* gsum, int n)
{
    int c = threadIdx.x & 127, sub = threadIdx.x >> 7;
    int r0 = blockIdx.x * 128;
    int rend = min(r0 + 128, n);
    float mx = 0.f, sm = 0.f;
    int cur = -1;
    for (int r = r0 + sub; r < rend; r += 2) {
        int b = batch[r];
        if (b != cur) {
            if (cur >= 0) {
                atomicMax((unsigned int*)&gmax[cur * 128 + c], __float_as_uint(mx));
                atomicAdd(&gsum[cur * 128 + c], sm);
            }
            cur = b; mx = 0.f; sm = 0.f;
        }
        float v = b2f(h[(size_t)r * 128 + c]);
        mx = fmaxf(mx, v);
        sm += v;
    }
    if (cur >= 0) {
        atomicMax((unsigned int*)&gmax[cur * 128 + c], __float_as_uint(mx));
        atomicAdd(&gsum[cur * 128 + c], sm);
    }
}

__global__ __launch_bounds__(256) void k_final(const float* __restrict__ gmax, const float* __restrict__ gsum,
                                               const float* __restrict__ cntG, float* __restrict__ out,
                                               int G, int L)
{
    int i = blockIdx.x * 256 + threadIdx.x;
    int tot = L * G * 128;
    if (i >= tot) return;
    int c = i & 127;
    int g = (i >> 7) % G;
    int l = i / (G * 128);
    float ct = fmaxf(cntG[g], 1.0f);
    out[(size_t)g * (L * 256) + l * 256 + c]       = gmax[i];
    out[(size_t)g * (L * 256) + l * 256 + 128 + c] = gsum[i] / ct;
}

static inline int divup(int a, int b) { return (a + b - 1) / b; }

extern "C" void kernel_launch(void* const* d_in, const int* in_sizes, int n_in,
                              void* d_out, int out_size, void* d_ws, size_t ws_size,
                              hipStream_t stream)
{
    const float* x     = (const float*)d_in[0];
    const float* ew    = (const float*)d_in[1];
    const float* W1    = (const float*)d_in[2];
    const float* b1    = (const float*)d_in[3];
    const float* W2    = (const float*)d_in[4];
    const float* b2    = (const float*)d_in[5];
    const float* cW    = (const float*)d_in[6];
    const float* cB    = (const float*)d_in[7];
    const int*   ei    = (const int*)d_in[8];
    const int*   batch = (const int*)d_in[9];
    float* out = (float*)d_out;

    const int E = in_sizes[1];
    const int N = in_sizes[9];
    const int L = in_sizes[7] / 128;
    const int G = out_size / (L * 256);

    char* p = (char*)d_ws;
    auto carve = [&](size_t bytes) -> void* {
        void* q = (void*)p;
        p += (bytes + 255) & ~(size_t)255;
        return q;
    };
    unsigned long long* pk = (unsigned long long*)carve((size_t)N * 8);
    float* dinv     = (float*)carve((size_t)N * 4);
    int*   start    = (int*)  carve((size_t)(N + 1) * 4);
    int*   eslot    = (int*)  carve((size_t)E * 4);
    int*   partials = (int*)  carve(4096);
    int*   csrc     = (int*)  carve((size_t)E * 4);
    float* cw       = (float*)carve((size_t)E * 4);
    float* gmax     = (float*)carve((size_t)L * G * 128 * 4);
    float* gsum     = (float*)carve((size_t)L * G * 128 * 4);
    float* cntG     = (float*)carve((size_t)G * 4);
    unsigned short* wf[5];
    for (int i = 0; i < 5; ++i) wf[i] = (unsigned short*)carve(16384 * 2);
    unsigned short* xwb = (unsigned short*)carve((size_t)N * 128 * 2);
    unsigned short* hbA = (unsigned short*)carve((size_t)N * 128 * 2);
    unsigned short* hbB = (unsigned short*)carve((size_t)N * 128 * 2);

    const int npool = L * G * 128;

    // --- preprocessing -----------------------------------------------------
    {
        int mx = N > npool ? N : npool;
        k_init<<<divup(mx, 256), 256, 0, stream>>>(pk, gmax, gsum, N, npool);
    }
    k_phase1<<<divup(E, 256), 256, 0, stream>>>(ei, ew, pk, eslot, E);
    k_dinv<<<divup(N, 256), 256, 0, stream>>>(pk, dinv, N);
    k_gcnt<<<1, 64, 0, stream>>>(batch, cntG, N, G);

    int nb1 = divup(N, 1024);
    k_scan1<<<nb1, 256, 0, stream>>>(pk, start, partials, N);
    k_scan2<<<1, 256, 0, stream>>>(partials, nb1);
    k_scan3<<<divup(N, 256), 256, 0, stream>>>(start, partials, N, E);
    k_phase2<<<divup(E, 256), 256, 0, stream>>>(ei, ew, dinv, start, eslot, csrc, cw, E);

    // --- weight fragment linearization ------------------------------------
    k_wfrag<<<8, 256, 0, stream>>>(W1, wf[0]);
    k_wfrag<<<8, 256, 0, stream>>>(W2, wf[1]);
    for (int l = 0; l < L && l < 3; ++l)
        k_wfrag<<<8, 256, 0, stream>>>(cW + (size_t)l * 16384, wf[2 + l]);

    // --- dense encoder -----------------------------------------------------
    int gblocks = divup(N, 64);
    k_gemm_mf<<<gblocks, 256, 0, stream>>>(nullptr, x, wf[0], b1, hbA, 1, N);
    k_gemm_mf<<<gblocks, 256, 0, stream>>>(hbA, nullptr, wf[1], b2, hbB, 1, N);

    // --- conv layers + pooling --------------------------------------------
    int ablocks = divup(N, 4);
    int pblocks = divup(N, 128);
    unsigned short* cur = hbB;
    unsigned short* alt = hbA;
    for (int l = 0; l < L; ++l) {
        k_gemm_mf<<<gblocks, 256, 0, stream>>>(cur, nullptr, wf[2 + (l < 3 ? l : 2)], nullptr, xwb, 0, N);
        k_agg<<<ablocks, 256, 0, stream>>>((const unsigned int*)xwb, start, csrc, cw, dinv,
                                           cB + (size_t)l * 128, (unsigned int*)alt, N);
        k_pool<<<pblocks, 256, 0, stream>>>(alt, batch, gmax + (size_t)l * G * 128,
                                            gsum + (size_t)l * G * 128, N);
        unsigned short* tmp = cur; cur = alt; alt = tmp;
    }

    k_final<<<divup(L * G * 128, 256), 256, 0, stream>>>(gmax, gsum, cntG, out, G, L);
}

// Round 6
// 520.208 us; speedup vs baseline: 3.4814x; 1.0442x over previous
//
#include <hip/hip_runtime.h>

// ---------------------------------------------------------------------------
// CustomGCN: 2 dense layers + 3 GCNConv layers + per-layer (max||mean) pool.
// R1: binary-search cntG (removed 634us atomic wall).
// R2: bf16 hidden pipeline; MFMA bf16 GEMMs; bf16 gather table.
// R3: k_agg 8-deep gather pipeline.
// R4: CSC build with ONE u64 atomic/edge (count<<52 | w*2^32), atomic-free fill.
// R5: CSC entries interleaved as one 8B record/edge (was 2x4B scattered stores
//     = 106MB write-allocate traffic in phase2; now ~53MB). dinv folded into
//     scan1.
// ---------------------------------------------------------------------------

typedef __attribute__((ext_vector_type(8))) short bf16x8;
typedef __attribute__((ext_vector_type(4))) float f32x4;
typedef unsigned long long u64;

#define FRACBITS 52
#define FRACMASK ((1ULL << FRACBITS) - 1ULL)

__device__ __forceinline__ unsigned short f2b(float f) {  // RNE f32->bf16
    unsigned int u = __float_as_uint(f);
    return (unsigned short)((u + 0x7fffu + ((u >> 16) & 1u)) >> 16);
}
__device__ __forceinline__ float b2f(unsigned short h) {
    return __uint_as_float((unsigned int)h << 16);
}

// ---------------- preprocessing --------------------------------------------
__global__ __launch_bounds__(256) void k_init(u64* __restrict__ pk,
                                              float* __restrict__ gmax, float* __restrict__ gsum,
                                              int n, int npool)
{
    int i = blockIdx.x * 256 + threadIdx.x;
    if (i < n) pk[i] = 0ULL;
    if (i < npool) { gmax[i] = 0.0f; gsum[i] = 0.0f; }
}

// one u64 atomic per edge: count in [52:63], weight-sum fixed-point in [0:51]
__global__ __launch_bounds__(256) void k_phase1(const int* __restrict__ ei,
                                                const float* __restrict__ ew,
                                                u64* pk,
                                                int* __restrict__ eslot, int e)
{
    int i = blockIdx.x * 256 + threadIdx.x;
    if (i >= e) return;
    int c = ei[e + i];
    float w = ew[i];
    u64 fixed = (u64)((double)w * 4294967296.0);
    u64 packed = (1ULL << FRACBITS) | fixed;
    u64 old = atomicAdd(&pk[c], packed);
    eslot[i] = (int)(old >> FRACBITS);
}

__global__ void k_gcnt(const int* __restrict__ batch, float* __restrict__ cntG, int n, int g)
{
    int t = threadIdx.x;
    if (t >= g) return;
    int lo0 = 0, hi0 = n;
    while (lo0 < hi0) { int m = (lo0 + hi0) >> 1; if (batch[m] < t) lo0 = m + 1; else hi0 = m; }
    int lo1 = lo0, hi1 = n, t1 = t + 1;
    while (lo1 < hi1) { int m = (lo1 + hi1) >> 1; if (batch[m] < t1) lo1 = m + 1; else hi1 = m; }
    cntG[t] = (float)(lo1 - lo0);
}

// ---- exclusive scan of counts (pk>>52) into start[0..n); also emits dinv ---
__global__ __launch_bounds__(256) void k_scan1(const u64* __restrict__ pk,
                                               int* __restrict__ start,
                                               float* __restrict__ dinv,
                                               int* __restrict__ partials, int n)
{
    __shared__ int s[256];
    int t = threadIdx.x;
    int base = blockIdx.x * 1024 + t * 4;
    int v[4];
#pragma unroll
    for (int j = 0; j < 4; ++j) {
        int idx = base + j;
        if (idx < n) {
            u64 q = pk[idx];
            v[j] = (int)(q >> FRACBITS);
            float deg = 1.0f + (float)((double)(q & FRACMASK) * (1.0 / 4294967296.0));
            dinv[idx] = 1.0f / sqrtf(deg);
        } else v[j] = 0;
    }
    int tsum = v[0] + v[1] + v[2] + v[3];
    s[t] = tsum; __syncthreads();
    for (int off = 1; off < 256; off <<= 1) {
        int xv = (t >= off) ? s[t - off] : 0;
        __syncthreads();
        s[t] += xv;
        __syncthreads();
    }
    if (t == 255) partials[blockIdx.x] = s[255];
    int run = s[t] - tsum;
#pragma unroll
    for (int j = 0; j < 4; ++j) { int idx = base + j; if (idx < n) start[idx] = run; run += v[j]; }
}

__global__ __launch_bounds__(256) void k_scan2(int* partials, int nb)
{
    __shared__ int s[256];
    int t = threadIdx.x;
    int offset = 0;
    for (int b0 = 0; b0 < nb; b0 += 256) {
        int v = (b0 + t < nb) ? partials[b0 + t] : 0;
        s[t] = v; __syncthreads();
        for (int off = 1; off < 256; off <<= 1) {
            int xv = (t >= off) ? s[t - off] : 0;
            __syncthreads();
            s[t] += xv;
            __syncthreads();
        }
        int excl = s[t] - v;
        int tot = s[255];
        if (b0 + t < nb) partials[b0 + t] = offset + excl;
        offset += tot;
        __syncthreads();
    }
}

__global__ __launch_bounds__(256) void k_scan3(int* __restrict__ start,
                                               const int* __restrict__ partials, int n, int total)
{
    int i = blockIdx.x * 256 + threadIdx.x;
    if (i < n) start[i] += partials[i >> 10];
    if (i == 0) start[n] = total;
}

// ---- atomic-free fill: one 8B record (src | w) per edge --------------------
__global__ __launch_bounds__(256) void k_phase2(const int* __restrict__ ei, const float* __restrict__ ew,
                                                const float* __restrict__ dinv,
                                                const int* __restrict__ start,
                                                const int* __restrict__ eslot,
                                                u64* __restrict__ rec, int e)
{
    int i = blockIdx.x * 256 + threadIdx.x;
    if (i >= e) return;
    int r = ei[i], c = ei[e + i];
    int idx = start[c] + eslot[i];
    float w = dinv[r] * ew[i] * dinv[c];
    rec[idx] = ((u64)__float_as_uint(w) << 32) | (unsigned int)r;
}

// ---------------- weight linearization into MFMA fragment order ------------
__global__ __launch_bounds__(256) void k_wfrag(const float* __restrict__ W, unsigned short* __restrict__ Wf)
{
    int idx = blockIdx.x * 256 + threadIdx.x;   // [0, 2048)
    if (idx >= 2048) return;
    int ctkt = idx >> 6, lane = idx & 63;
    int kt = ctkt & 3, ct = ctkt >> 2;
    int k0 = kt * 32 + (lane >> 4) * 8;
    int col = ct * 16 + (lane & 15);
    bf16x8 v;
#pragma unroll
    for (int j = 0; j < 8; ++j) v[j] = (short)f2b(W[(k0 + j) * 128 + col]);
    *(bf16x8*)&Wf[(size_t)idx * 8] = v;
}

// ---------------- MFMA GEMM: C[M,128] = A[M,128] @ W[128,128] --------------
__global__ __launch_bounds__(256) void k_gemm_mf(const unsigned short* __restrict__ A,
                                                 const float* __restrict__ Af32,
                                                 const unsigned short* __restrict__ Wf,
                                                 const float* __restrict__ bias,
                                                 unsigned short* __restrict__ C,
                                                 int relu, int M)
{
    int t = threadIdx.x;
    int lane = t & 63, w = t >> 6;
    int s = blockIdx.x * 4 + w;
    if (s * 16 >= M) return;
    int r0 = s * 16;
    int row = r0 + (lane & 15);
    int k0 = (lane >> 4) * 8;

    bf16x8 af[4];
    if (A) {
#pragma unroll
        for (int kt = 0; kt < 4; ++kt) {
            bf16x8 a = {0,0,0,0,0,0,0,0};
            if (row < M) a = *(const bf16x8*)&A[(size_t)row * 128 + k0 + kt * 32];
            af[kt] = a;
        }
    } else {
#pragma unroll
        for (int kt = 0; kt < 4; ++kt) {
            bf16x8 a = {0,0,0,0,0,0,0,0};
            if (row < M) {
                const float4* A4 = (const float4*)(Af32 + (size_t)row * 128 + k0 + kt * 32);
                float4 p = A4[0], q = A4[1];
                a[0] = (short)f2b(p.x); a[1] = (short)f2b(p.y);
                a[2] = (short)f2b(p.z); a[3] = (short)f2b(p.w);
                a[4] = (short)f2b(q.x); a[5] = (short)f2b(q.y);
                a[6] = (short)f2b(q.z); a[7] = (short)f2b(q.w);
            }
            af[kt] = a;
        }
    }

    int orow = r0 + 4 * (lane >> 4);
    int ocol = lane & 15;
#pragma unroll
    for (int ct = 0; ct < 8; ++ct) {
        f32x4 acc = {0.f, 0.f, 0.f, 0.f};
#pragma unroll
        for (int kt = 0; kt < 4; ++kt) {
            bf16x8 b = *(const bf16x8*)&Wf[(size_t)(((ct << 2) | kt) * 64 + lane) * 8];
            acc = __builtin_amdgcn_mfma_f32_16x16x32_bf16(af[kt], b, acc, 0, 0, 0);
        }
        float bv = bias ? bias[ct * 16 + ocol] : 0.f;
#pragma unroll
        for (int j = 0; j < 4; ++j) {
            int rr = orow + j;
            if (rr < M) {
                float v = acc[j] + bv;
                if (relu) v = fmaxf(v, 0.f);
                C[(size_t)rr * 128 + ct * 16 + ocol] = f2b(v);
            }
        }
    }
}

// ---------------- pull aggregation: 8-deep gather pipeline -----------------
__global__ __launch_bounds__(256) void k_agg(const unsigned int* __restrict__ xw,
                                             const int* __restrict__ start,
                                             const u64* __restrict__ rec,
                                             const float* __restrict__ dinv, const float* __restrict__ bias,
                                             unsigned int* __restrict__ hout, int n)
{
    int wid  = (blockIdx.x * 256 + threadIdx.x) >> 6;
    int lane = threadIdx.x & 63;
    if (wid >= n) return;
    float di = dinv[wid];
    float sn = di * di;
    unsigned int v = xw[(size_t)wid * 64 + lane];
    float ax = __uint_as_float(v << 16) * sn;
    float ay = __uint_as_float(v & 0xffff0000u) * sn;
    int s0 = start[wid], s1 = start[wid + 1];

    int j = s0;
    for (; j + 8 <= s1; j += 8) {
        u64 rc[8];
#pragma unroll
        for (int q = 0; q < 8; ++q) rc[q] = rec[j + q];
        unsigned int u[8];
#pragma unroll
        for (int q = 0; q < 8; ++q) u[q] = xw[(size_t)(unsigned int)rc[q] * 64 + lane];
#pragma unroll
        for (int q = 0; q < 8; ++q) {
            float w = __uint_as_float((unsigned int)(rc[q] >> 32));
            ax = fmaf(w, __uint_as_float(u[q] << 16), ax);
            ay = fmaf(w, __uint_as_float(u[q] & 0xffff0000u), ay);
        }
    }
    {
        int rem = s1 - j;
        u64 rc[8];
#pragma unroll
        for (int q = 0; q < 8; ++q) rc[q] = (q < rem) ? rec[j + q] : 0ULL;
        unsigned int u[8];
#pragma unroll
        for (int q = 0; q < 8; ++q) u[q] = (q < rem) ? xw[(size_t)(unsigned int)rc[q] * 64 + lane] : 0u;
#pragma unroll
        for (int q = 0; q < 8; ++q) {
            float w = __uint_as_float((unsigned int)(rc[q] >> 32));
            ax = fmaf(w, __uint_as_float(u[q] << 16), ax);
            ay = fmaf(w, __uint_as_float(u[q] & 0xffff0000u), ay);
        }
    }

    ax = fmaxf(ax + bias[lane * 2], 0.f);
    ay = fmaxf(ay + bias[lane * 2 + 1], 0.f);
    hout[(size_t)wid * 64 + lane] = (unsigned int)f2b(ax) | ((unsigned int)f2b(ay) << 16);
}

// ---------------- pooling (bf16 in) ----------------------------------------
__global__ __launch_bounds__(256) void k_pool(const unsigned short* __restrict__ h,
                                              const int* __restrict__ batch,
                                              float* gmax, float* gsum, int n)
{
    int c = threadIdx.x & 127, sub = threadIdx.x >> 7;
    int r0 = blockIdx.x * 128;
    int rend = min(r0 + 128, n);
    float mx = 0.f, sm = 0.f;
    int cur = -1;
    for (int r = r0 + sub; r < rend; r += 2) {
        int b = batch[r];
        if (b != cur) {
            if (cur >= 0) {
                atomicMax((unsigned int*)&gmax[cur * 128 + c], __float_as_uint(mx));
                atomicAdd(&gsum[cur * 128 + c], sm);
            }
            cur = b; mx = 0.f; sm = 0.f;
        }
        float v = b2f(h[(size_t)r * 128 + c]);
        mx = fmaxf(mx, v);
        sm += v;
    }
    if (cur >= 0) {
        atomicMax((unsigned int*)&gmax[cur * 128 + c], __float_as_uint(mx));
        atomicAdd(&gsum[cur * 128 + c], sm);
    }
}

__global__ __launch_bounds__(256) void k_final(const float* __restrict__ gmax, const float* __restrict__ gsum,
                                               const float* __restrict__ cntG, float* __restrict__ out,
                                               int G, int L)
{
    int i = blockIdx.x * 256 + threadIdx.x;
    int tot = L * G * 128;
    if (i >= tot) return;
    int c = i & 127;
    int g = (i >> 7) % G;
    int l = i / (G * 128);
    float ct = fmaxf(cntG[g], 1.0f);
    out[(size_t)g * (L * 256) + l * 256 + c]       = gmax[i];
    out[(size_t)g * (L * 256) + l * 256 + 128 + c] = gsum[i] / ct;
}

static inline int divup(int a, int b) { return (a + b - 1) / b; }

extern "C" void kernel_launch(void* const* d_in, const int* in_sizes, int n_in,
                              void* d_out, int out_size, void* d_ws, size_t ws_size,
                              hipStream_t stream)
{
    const float* x     = (const float*)d_in[0];
    const float* ew    = (const float*)d_in[1];
    const float* W1    = (const float*)d_in[2];
    const float* b1    = (const float*)d_in[3];
    const float* W2    = (const float*)d_in[4];
    const float* b2    = (const float*)d_in[5];
    const float* cW    = (const float*)d_in[6];
    const float* cB    = (const float*)d_in[7];
    const int*   ei    = (const int*)d_in[8];
    const int*   batch = (const int*)d_in[9];
    float* out = (float*)d_out;

    const int E = in_sizes[1];
    const int N = in_sizes[9];
    const int L = in_sizes[7] / 128;
    const int G = out_size / (L * 256);

    char* p = (char*)d_ws;
    auto carve = [&](size_t bytes) -> void* {
        void* q = (void*)p;
        p += (bytes + 255) & ~(size_t)255;
        return q;
    };
    u64*   pk       = (u64*)  carve((size_t)N * 8);
    float* dinv     = (float*)carve((size_t)N * 4);
    int*   start    = (int*)  carve((size_t)(N + 1) * 4);
    int*   eslot    = (int*)  carve((size_t)E * 4);
    int*   partials = (int*)  carve(4096);
    u64*   rec      = (u64*)  carve((size_t)E * 8);
    float* gmax     = (float*)carve((size_t)L * G * 128 * 4);
    float* gsum     = (float*)carve((size_t)L * G * 128 * 4);
    float* cntG     = (float*)carve((size_t)G * 4);
    unsigned short* wf[5];
    for (int i = 0; i < 5; ++i) wf[i] = (unsigned short*)carve(16384 * 2);
    unsigned short* xwb = (unsigned short*)carve((size_t)N * 128 * 2);
    unsigned short* hbA = (unsigned short*)carve((size_t)N * 128 * 2);
    unsigned short* hbB = (unsigned short*)carve((size_t)N * 128 * 2);

    const int npool = L * G * 128;

    // --- preprocessing -----------------------------------------------------
    {
        int mx = N > npool ? N : npool;
        k_init<<<divup(mx, 256), 256, 0, stream>>>(pk, gmax, gsum, N, npool);
    }
    k_phase1<<<divup(E, 256), 256, 0, stream>>>(ei, ew, pk, eslot, E);
    k_gcnt<<<1, 64, 0, stream>>>(batch, cntG, N, G);

    int nb1 = divup(N, 1024);
    k_scan1<<<nb1, 256, 0, stream>>>(pk, start, dinv, partials, N);
    k_scan2<<<1, 256, 0, stream>>>(partials, nb1);
    k_scan3<<<divup(N, 256), 256, 0, stream>>>(start, partials, N, E);
    k_phase2<<<divup(E, 256), 256, 0, stream>>>(ei, ew, dinv, start, eslot, rec, E);

    // --- weight fragment linearization ------------------------------------
    k_wfrag<<<8, 256, 0, stream>>>(W1, wf[0]);
    k_wfrag<<<8, 256, 0, stream>>>(W2, wf[1]);
    for (int l = 0; l < L && l < 3; ++l)
        k_wfrag<<<8, 256, 0, stream>>>(cW + (size_t)l * 16384, wf[2 + l]);

    // --- dense encoder -----------------------------------------------------
    int gblocks = divup(N, 64);
    k_gemm_mf<<<gblocks, 256, 0, stream>>>(nullptr, x, wf[0], b1, hbA, 1, N);
    k_gemm_mf<<<gblocks, 256, 0, stream>>>(hbA, nullptr, wf[1], b2, hbB, 1, N);

    // --- conv layers + pooling --------------------------------------------
    int ablocks = divup(N, 4);
    int pblocks = divup(N, 128);
    unsigned short* cur = hbB;
    unsigned short* alt = hbA;
    for (int l = 0; l < L; ++l) {
        k_gemm_mf<<<gblocks, 256, 0, stream>>>(cur, nullptr, wf[2 + (l < 3 ? l : 2)], nullptr, xwb, 0, N);
        k_agg<<<ablocks, 256, 0, stream>>>((const unsigned int*)xwb, start, rec, dinv,
                                           cB + (size_t)l * 128, (unsigned int*)alt, N);
        k_pool<<<pblocks, 256, 0, stream>>>(alt, batch, gmax + (size_t)l * G * 128,
                                            gsum + (size_t)l * G * 128, N);
        unsigned short* tmp = cur; cur = alt; alt = tmp;
    }

    k_final<<<divup(L * G * 128, 256), 256, 0, stream>>>(gmax, gsum, cntG, out, G, L);
}